// Round 5
// baseline (968.232 us; speedup 1.0000x reference)
//
#include <hip/hip_runtime.h>

// ---------------------------------------------------------------------------
// Round 5: whole FC stack -> bf16 MFMA (R4 profile: fp32 split-K fc_kernel
// ~100us each, VALUBusy 16%, MfmaUtil 0). Weights repacked to B-frag layout
// per launch; activations flow bf16; 8-way split-K + tiny fp32 reduce.
// GIN path (CSR gather + MFMA gin_pool) unchanged from R4.
// ---------------------------------------------------------------------------

static constexpr int NG = 256;  // number of graphs

typedef short  short8  __attribute__((ext_vector_type(8)));
typedef float  floatx4 __attribute__((ext_vector_type(4)));

__device__ __forceinline__ short f2bf(float f) {
    unsigned u = __float_as_uint(f);
    u += 0x7fff + ((u >> 16) & 1);          // RNE to bf16
    return (short)(u >> 16);
}

// ---- segment bookkeeping ---------------------------------------------------
__global__ void hist_kernel(const int* __restrict__ seg, int N, int* __restrict__ cnt) {
    int i = blockIdx.x * blockDim.x + threadIdx.x;
    if (i < N) atomicAdd(&cnt[seg[i]], 1);
}

__global__ void seg_scan_kernel(const int* __restrict__ cnt, int* __restrict__ offs) {
    if (threadIdx.x == 0) {
        int acc = 0;
        for (int g = 0; g < NG; ++g) { offs[g] = acc; acc += cnt[g]; }
        offs[NG] = acc;
    }
}

// ---- CSR build: histogram dst -> prefix scan -> fill ----------------------
__global__ void deg_kernel(const int* __restrict__ ei, int E, int* __restrict__ deg) {
    int e = blockIdx.x * blockDim.x + threadIdx.x;
    if (e < E) atomicAdd(&deg[ei[E + e]], 1);   // dst = ei[E+e]
}

__global__ __launch_bounds__(256) void scan1_kernel(const int* __restrict__ deg, int N,
                                                    int* __restrict__ excl,
                                                    int* __restrict__ bsum) {
    __shared__ int sh[256];
    int base = blockIdx.x * 1024;
    int t = threadIdx.x;
    int v[4];
    int s = 0;
    #pragma unroll
    for (int i = 0; i < 4; ++i) {
        int idx = base + t * 4 + i;
        v[i] = s;
        s += (idx < N) ? deg[idx] : 0;
    }
    sh[t] = s;
    __syncthreads();
    for (int off = 1; off < 256; off <<= 1) {
        int xv = (t >= off) ? sh[t - off] : 0;
        __syncthreads();
        sh[t] += xv;
        __syncthreads();
    }
    int texcl = (t > 0) ? sh[t - 1] : 0;
    #pragma unroll
    for (int i = 0; i < 4; ++i) {
        int idx = base + t * 4 + i;
        if (idx < N) excl[idx] = texcl + v[i];
    }
    if (t == 255) bsum[blockIdx.x] = sh[255];
}

__global__ void scan2_kernel(int* __restrict__ bsum, int nb) {
    if (threadIdx.x == 0) {
        int acc = 0;
        for (int i = 0; i < nb; ++i) { int t = bsum[i]; bsum[i] = acc; acc += t; }
    }
}

__global__ void scan3_kernel(int* __restrict__ excl, const int* __restrict__ bsum,
                             int N, int E) {
    int i = blockIdx.x * blockDim.x + threadIdx.x;
    if (i < N) excl[i] += bsum[i >> 10];
    if (i == 0) excl[N] = E;
}

__global__ void copy_kernel(int* __restrict__ dst, const int* __restrict__ src, int N) {
    int i = blockIdx.x * blockDim.x + threadIdx.x;
    if (i < N) dst[i] = src[i];
}

__global__ void fill_csr_kernel(const int* __restrict__ ei, int E,
                                int* __restrict__ cursor, int* __restrict__ csr) {
    int e = blockIdx.x * blockDim.x + threadIdx.x;
    if (e < E) {
        int dst = ei[E + e];
        int pos = atomicAdd(&cursor[dst], 1);
        csr[pos] = ei[e];                    // src
    }
}

// ---- gather: agg[n] = sum_{e: dst==n} x[src_e]  (wave per node) -----------
template<int F>
__global__ __launch_bounds__(256) void gather_kernel(const float* __restrict__ x,
        const int* __restrict__ csr, const int* __restrict__ ro,
        float* __restrict__ agg, int N) {
    int wave = (blockIdx.x * 256 + threadIdx.x) >> 6;
    int lane = threadIdx.x & 63;
    if (wave >= N) return;
    int s = ro[wave], e = ro[wave + 1];
    float a0 = 0.f, a1 = 0.f;
    const bool l0 = lane < F;
    const bool l1 = (lane + 64) < F;
    for (int i = s; i < e; ++i) {
        const float* row = x + (size_t)csr[i] * F;
        if (l0) a0 += row[lane];
        if (l1) a1 += row[lane + 64];
    }
    float* o = agg + (size_t)wave * F;
    if (l0) o[lane] = a0;
    if (l1) o[lane + 64] = a1;
}

// ---- GIN layer 1: out = relu((x+agg) @ W + b), F -> F ---------------------
template<int F, int BD>
__global__ __launch_bounds__(BD) void gin_linear_kernel(
        const float* __restrict__ x, const float* __restrict__ agg,
        const float* __restrict__ W, const float* __restrict__ b,
        float* __restrict__ out, int N) {
    constexpr int TILE = 32, PAD = 36;
    __shared__ __align__(16) float Vt[F][PAD];
    int node0 = blockIdx.x * TILE;
    if (node0 >= N) return;
    int nvalid = N - node0; if (nvalid > TILE) nvalid = TILE;
    if (nvalid < TILE) {
        for (int idx = threadIdx.x; idx < F * TILE; idx += BD)
            Vt[idx % F][idx / F] = 0.f;
        __syncthreads();
    }
    int total = nvalid * F;
    const float* xs = x + (size_t)node0 * F;
    const float* as = agg + (size_t)node0 * F;
    for (int f = threadIdx.x; f < total; f += BD)
        Vt[f % F][f / F] = xs[f] + as[f];
    __syncthreads();
    int j = threadIdx.x;
    if (j < F) {
        float acc[TILE];
        #pragma unroll
        for (int n = 0; n < TILE; ++n) acc[n] = 0.f;
        for (int k = 0; k < F; ++k) {
            float w = W[k * F + j];
            const float4* row = (const float4*)&Vt[k][0];
            #pragma unroll
            for (int q = 0; q < TILE / 4; ++q) {
                float4 a = row[q];
                acc[q * 4 + 0] += a.x * w;
                acc[q * 4 + 1] += a.y * w;
                acc[q * 4 + 2] += a.z * w;
                acc[q * 4 + 3] += a.w * w;
            }
        }
        float bj = b[j];
        for (int n = 0; n < nvalid; ++n)
            out[(size_t)(node0 + n) * F + j] = fmaxf(acc[n] + bj, 0.f);
    }
}

// ---- W repack for MFMA B-fragments: W[F][FO] fp32 -> Wb[NT*16][KP] bf16 ---
template<int F, int KP, int FO, int NT>
__global__ void repack_w_kernel(const float* __restrict__ W, short* __restrict__ Wb) {
    int id = blockIdx.x * blockDim.x + threadIdx.x;   // col index incl. pad
    if (id >= NT * 16) return;
    for (int k = 0; k < KP; ++k) {
        float v = (k < F && id < FO) ? W[(size_t)k * FO + id] : 0.f;
        Wb[(size_t)id * KP + k] = f2bf(v);
    }
}

// ---- generic fc weight repack: W[K][N] fp32 -> Wb[N][KP] bf16 (zero-pad K)
__global__ __launch_bounds__(256) void repack_fc_kernel(
        const float* __restrict__ W, short* __restrict__ Wb,
        int K, int N, int KP) {
    int col = blockIdx.x * 256 + threadIdx.x;
    if (col >= N) return;
    int k0 = blockIdx.y * 64;
    int k1 = k0 + 64; if (k1 > KP) k1 = KP;
    for (int k = k0; k < k1; ++k) {
        float v = (k < K) ? W[(size_t)k * N + col] : 0.f;
        Wb[(size_t)col * KP + k] = f2bf(v);
    }
}

// ---- fused GIN layer 2 + pool, bf16 MFMA ----------------------------------
template<int F, int KP, int FO, int NT, int NS>
__global__ __launch_bounds__(256) void gin_pool_mfma_kernel(
        const float* __restrict__ h, const float* __restrict__ agg,
        const short* __restrict__ Wb, const float* __restrict__ b,
        const int* __restrict__ offs,
        float* __restrict__ ppmax, float* __restrict__ ppsum) {
    constexpr int KK = KP / 32;
    __shared__ __align__(16) short Vb[64][KP];
    __shared__ float pmaxL[NT * 16];
    __shared__ float psumL[NT * 16];
    int g = blockIdx.x / NS;
    int s = blockIdx.x % NS;
    int tid = threadIdx.x;
    int wid = tid >> 6;
    int lane = tid & 63;
    int ln = lane & 15;
    int quad = lane >> 4;

    int gs0 = offs[g], ge0 = offs[g + 1];
    int per = (ge0 - gs0 + NS - 1) / NS;
    int gs = gs0 + s * per;
    int ge = gs + per; if (ge > ge0) ge = ge0;

    for (int i = tid; i < NT * 16; i += 256) { pmaxL[i] = 0.f; psumL[i] = 0.f; }
    for (int i = tid; i < 64 * (KP - F); i += 256)
        Vb[i / (KP - F)][F + i % (KP - F)] = 0;

    for (int c0 = gs; c0 < ge; c0 += 64) {
        __syncthreads();
        int cvalid = ge - c0; if (cvalid > 64) cvalid = 64;
        int nelem = cvalid * F;
        const float* hs = h + (size_t)c0 * F;
        const float* as = agg + (size_t)c0 * F;
        for (int idx = tid; idx < nelem; idx += 256)
            Vb[idx / F][idx % F] = f2bf(hs[idx] + as[idx]);
        __syncthreads();
        short8 afr[KK][4];
        #pragma unroll
        for (int kk = 0; kk < KK; ++kk)
            #pragma unroll
            for (int ms = 0; ms < 4; ++ms)
                afr[kk][ms] = *(const short8*)&Vb[ms * 16 + ln][kk * 32 + quad * 8];
        for (int nt = wid; nt < NT; nt += 4) {
            int col = nt * 16 + ln;
            float bcol = (col < FO) ? b[col] : 0.f;
            short8 bfr[KK];
            const short8* bp = (const short8*)(Wb + (size_t)col * KP + quad * 8);
            #pragma unroll
            for (int kk = 0; kk < KK; ++kk) bfr[kk] = bp[kk * 4];
            float cmx = 0.f, csm = 0.f;
            #pragma unroll
            for (int ms = 0; ms < 4; ++ms) {
                if (ms * 16 < cvalid) {
                    floatx4 acc = {0.f, 0.f, 0.f, 0.f};
                    #pragma unroll
                    for (int kk = 0; kk < KK; ++kk)
                        acc = __builtin_amdgcn_mfma_f32_16x16x32_bf16(
                                  afr[kk][ms], bfr[kk], acc, 0, 0, 0);
                    #pragma unroll
                    for (int r = 0; r < 4; ++r) {
                        int rowl = ms * 16 + quad * 4 + r;
                        float v = fmaxf(acc[r] + bcol, 0.f);
                        if (rowl < cvalid) { cmx = fmaxf(cmx, v); csm += v; }
                    }
                }
            }
            cmx = fmaxf(cmx, __shfl_xor(cmx, 16, 64));
            cmx = fmaxf(cmx, __shfl_xor(cmx, 32, 64));
            csm += __shfl_xor(csm, 16, 64);
            csm += __shfl_xor(csm, 32, 64);
            if (quad == 0) {
                int i = nt * 16 + ln;
                pmaxL[i] = fmaxf(pmaxL[i], cmx);
                psumL[i] += csm;
            }
        }
    }
    __syncthreads();
    float* om = ppmax + (size_t)(g * NS + s) * FO;
    float* os = ppsum + (size_t)(g * NS + s) * FO;
    for (int col = tid; col < FO; col += 256) { om[col] = pmaxL[col]; os[col] = psumL[col]; }
}

// ---- combine partial pools -> pb bf16 [NG][KPAD]: [max | mean | 0-pad] ----
template<int FO, int NS, int KPAD>
__global__ __launch_bounds__(256) void pool_reduce_kernel(
        const float* __restrict__ ppmax, const float* __restrict__ ppsum,
        const int* __restrict__ offs, short* __restrict__ pb) {
    int g = blockIdx.x;
    int cntg = offs[g + 1] - offs[g];
    float den = (float)(cntg > 0 ? cntg : 1);
    for (int col = threadIdx.x; col < KPAD; col += 256) {
        float v = 0.f;
        if (col < FO) {
            float m = 0.f;
            #pragma unroll
            for (int ss = 0; ss < NS; ++ss)
                m = fmaxf(m, ppmax[(size_t)(g * NS + ss) * FO + col]);
            v = m;
        } else if (col < 2 * FO) {
            float sm = 0.f;
            #pragma unroll
            for (int ss = 0; ss < NS; ++ss)
                sm += ppsum[(size_t)(g * NS + ss) * FO + (col - FO)];
            v = sm / den;
        }
        pb[(size_t)g * KPAD + col] = f2bf(v);
    }
}

// ---- bf16 MFMA GEMM, split-K: partial[ks] = Ab[256,KP] @ Wb[N,KP]^T -------
// block = 64 rows x 64 cols x K-chunk KPC; 4 waves (wave w -> rows w*16..).
// A/B frags loaded straight from global (L2-hot bf16), no LDS.
template<int KPC>
__global__ __launch_bounds__(256) void fc_mfma_kernel(
        const short* __restrict__ Ab, const short* __restrict__ Wb,
        float* __restrict__ partial, int KP, int NB) {
    int bid = blockIdx.x;
    int mb = bid & 3;                 // M = 256 -> 4 row-tiles of 64
    int nb = (bid >> 2) % NB;
    int ks = (bid >> 2) / NB;
    int tid = threadIdx.x;
    int w = tid >> 6;
    int lane = tid & 63;
    int ln = lane & 15, quad = lane >> 4;
    int row = mb * 64 + w * 16 + ln;
    const short* ap = Ab + (size_t)row * KP + ks * KPC + quad * 8;
    const short* wp = Wb + (size_t)(nb * 64 + ln) * KP + ks * KPC + quad * 8;
    floatx4 acc[4];
    #pragma unroll
    for (int ns = 0; ns < 4; ++ns) acc[ns] = {0.f, 0.f, 0.f, 0.f};
    #pragma unroll
    for (int kk = 0; kk < KPC / 32; ++kk) {
        short8 a = *(const short8*)(ap + kk * 32);
        #pragma unroll
        for (int ns = 0; ns < 4; ++ns) {
            short8 b = *(const short8*)(wp + (size_t)ns * 16 * KP + kk * 32);
            acc[ns] = __builtin_amdgcn_mfma_f32_16x16x32_bf16(a, b, acc[ns], 0, 0, 0);
        }
    }
    int N = NB * 64;
    float* pp = partial + ((size_t)ks * 256 + mb * 64 + w * 16) * N + nb * 64;
    #pragma unroll
    for (int ns = 0; ns < 4; ++ns)
        #pragma unroll
        for (int r = 0; r < 4; ++r)
            pp[(quad * 4 + r) * N + ns * 16 + ln] = acc[ns][r];
}

// ---- split-K reduce: out = (relu?)(sum_ks partial + bias) -----------------
template<int KS, bool RELU, bool WBF16, bool WF32>
__global__ __launch_bounds__(256) void fc_reduce_kernel(
        const float* __restrict__ partial, const float* __restrict__ bias,
        short* __restrict__ outb, float* __restrict__ outf, int MN, int N) {
    int idx = blockIdx.x * 256 + threadIdx.x;
    if (idx >= MN) return;
    float v = bias[idx % N];
    #pragma unroll
    for (int s = 0; s < KS; ++s) v += partial[(size_t)s * MN + idx];
    if (RELU) v = fmaxf(v, 0.f);
    if (WBF16) outb[idx] = f2bf(v);
    if (WF32)  outf[idx] = v;
}

// ---- final head dot: z[row] = dot(t2[row,:256], w) + b[0] ------------------
__global__ __launch_bounds__(256) void final_dot_kernel(
        const float* __restrict__ A, const float* __restrict__ w,
        const float* __restrict__ b, float* __restrict__ z) {
    int row = blockIdx.x;
    int tid = threadIdx.x;
    float v = A[(size_t)row * 256 + tid] * w[tid];
    #pragma unroll
    for (int o = 32; o > 0; o >>= 1) v += __shfl_down(v, o, 64);
    __shared__ float red[4];
    if ((tid & 63) == 0) red[tid >> 6] = v;
    __syncthreads();
    if (tid == 0) z[row] = red[0] + red[1] + red[2] + red[3] + b[0];
}

// ---------------------------------------------------------------------------
static inline int cdiv(int a, int b) { return (a + b - 1) / b; }

// KP1 = padded K for fc1 (2048 branch1 / 1024 branch2); fc2 K=1024, fc3 K=512.
template<int F, int KPg, int FO, int NT, int BD_LIN, int KP1>
static void run_branch(const float* feat, const int* ei, int E, int N,
                       const int* seg,
                       const float* W1, const float* b1,
                       const float* W2, const float* b2,
                       const float* fw1, const float* fb1,
                       const float* fw2, const float* fb2,
                       const float* hw1, const float* hb1,
                       const float* hw2, const float* hb2,
                       float* agg, float* h1,
                       short* pb, short* t1b, short* xgb, float* t2,
                       float* ppmax, float* ppsum, short* Wbg,
                       short* Wb1, short* Wb2, short* Wb3, float* partial,
                       int* cnt, int* offs, int* deg, int* rowoff, int* cursor,
                       int* csr, int* bsum,
                       float* xg_out, float* z_out, hipStream_t stream) {
    constexpr int NS = 4;
    constexpr int KS = 8;
    // graph segment offsets
    hipMemsetAsync(cnt, 0, NG * sizeof(int), stream);
    hist_kernel<<<cdiv(N, 256), 256, 0, stream>>>(seg, N, cnt);
    seg_scan_kernel<<<1, 64, 0, stream>>>(cnt, offs);

    // CSR build
    hipMemsetAsync(deg, 0, N * sizeof(int), stream);
    deg_kernel<<<cdiv(E, 256), 256, 0, stream>>>(ei, E, deg);
    int nb = cdiv(N, 1024);
    scan1_kernel<<<nb, 256, 0, stream>>>(deg, N, rowoff, bsum);
    scan2_kernel<<<1, 64, 0, stream>>>(bsum, nb);
    scan3_kernel<<<cdiv(N, 256), 256, 0, stream>>>(rowoff, bsum, N, E);
    copy_kernel<<<cdiv(N, 256), 256, 0, stream>>>(cursor, rowoff, N);
    fill_csr_kernel<<<cdiv(E, 256), 256, 0, stream>>>(ei, E, cursor, csr);

    // GIN W2 -> bf16 B-fragment layout
    repack_w_kernel<F, KPg, FO, NT><<<cdiv(NT * 16, 256), 256, 0, stream>>>(W2, Wbg);

    // GIN layer 1
    gather_kernel<F><<<cdiv(N, 4), 256, 0, stream>>>(feat, csr, rowoff, agg, N);
    gin_linear_kernel<F, BD_LIN><<<cdiv(N, 32), BD_LIN, 0, stream>>>(feat, agg, W1, b1, h1, N);

    // GIN layer 2 fused with pooling (MFMA)
    gather_kernel<F><<<cdiv(N, 4), 256, 0, stream>>>(h1, csr, rowoff, agg, N);
    gin_pool_mfma_kernel<F, KPg, FO, NT, NS><<<NG * NS, 256, 0, stream>>>(
        h1, agg, Wbg, b2, offs, ppmax, ppsum);

    // fc weight repacks (Wb1..3 alias the h1 region -- h1 is dead after
    // gin_pool_mfma; stream order guarantees safety)
    {
        dim3 g1(cdiv(1024, 256), cdiv(KP1, 64));
        repack_fc_kernel<<<g1, 256, 0, stream>>>(fw1, Wb1, 2 * FO, 1024, KP1);
        dim3 g2(cdiv(512, 256), cdiv(1024, 64));
        repack_fc_kernel<<<g2, 256, 0, stream>>>(fw2, Wb2, 1024, 512, 1024);
        dim3 g3(cdiv(256, 256), cdiv(512, 64));
        repack_fc_kernel<<<g3, 256, 0, stream>>>(hw1, Wb3, 512, 256, 512);
    }

    // pool partials -> pb bf16 [256][KP1]
    pool_reduce_kernel<FO, NS, KP1><<<NG, 256, 0, stream>>>(ppmax, ppsum, offs, pb);

    // fc1: pb[256,KP1] @ Wb1 -> t1b[256,1024] (relu)
    fc_mfma_kernel<KP1 / KS><<<4 * 16 * KS, 256, 0, stream>>>(pb, Wb1, partial, KP1, 16);
    fc_reduce_kernel<KS, true, true, false><<<cdiv(256 * 1024, 256), 256, 0, stream>>>(
        partial, fb1, t1b, nullptr, 256 * 1024, 1024);

    // fc2: t1b[256,1024] @ Wb2 -> xg fp32 (output) + xgb bf16 (no relu)
    fc_mfma_kernel<1024 / KS><<<4 * 8 * KS, 256, 0, stream>>>(t1b, Wb2, partial, 1024, 8);
    fc_reduce_kernel<KS, false, true, true><<<cdiv(256 * 512, 256), 256, 0, stream>>>(
        partial, fb2, xgb, xg_out, 256 * 512, 512);

    // fc3 (head layer 1): xgb[256,512] @ Wb3 -> t2 fp32 [256,256] (relu)
    fc_mfma_kernel<512 / KS><<<4 * 4 * KS, 256, 0, stream>>>(xgb, Wb3, partial, 512, 4);
    fc_reduce_kernel<KS, true, false, true><<<cdiv(256 * 256, 256), 256, 0, stream>>>(
        partial, hb1, nullptr, t2, 256 * 256, 256);

    // final dot -> z
    final_dot_kernel<<<NG, 256, 0, stream>>>(t2, hw2, hb2, z_out);
}

extern "C" void kernel_launch(void* const* d_in, const int* in_sizes, int n_in,
                              void* d_out, int out_size, void* d_ws, size_t ws_size,
                              hipStream_t stream) {
    (void)n_in; (void)out_size; (void)ws_size;
    const float* x      = (const float*)d_in[1];
    const int*   ei     = (const int*)  d_in[2];
    const int*   batch  = (const int*)  d_in[3];
    const float* a      = (const float*)d_in[4];
    const int*   ed     = (const int*)  d_in[5];
    const int*   c      = (const int*)  d_in[6];
    const float* W1  = (const float*)d_in[7],  *b1  = (const float*)d_in[8];
    const float* W2  = (const float*)d_in[9],  *b2  = (const float*)d_in[10];
    const float* W3  = (const float*)d_in[11], *b3  = (const float*)d_in[12];
    const float* W4  = (const float*)d_in[13], *b4  = (const float*)d_in[14];
    const float* fg_w1  = (const float*)d_in[15], *fg_b1  = (const float*)d_in[16];
    const float* fg_w2  = (const float*)d_in[17], *fg_b2  = (const float*)d_in[18];
    const float* fg1_w1 = (const float*)d_in[19], *fg1_b1 = (const float*)d_in[20];
    const float* fg1_w2 = (const float*)d_in[21], *fg1_b2 = (const float*)d_in[22];
    const float* ff_w1  = (const float*)d_in[23], *ff_b1  = (const float*)d_in[24];
    const float* ff_w2  = (const float*)d_in[25], *ff_b2  = (const float*)d_in[26];
    const float* ff1_w1 = (const float*)d_in[27], *ff1_b1 = (const float*)d_in[28];
    const float* ff1_w2 = (const float*)d_in[29], *ff1_b2 = (const float*)d_in[30];

    const int N1 = in_sizes[1] / 93;
    const int E1 = in_sizes[2] / 2;
    const int N2 = in_sizes[4] / 43;
    const int E2 = in_sizes[5] / 2;

    float* out = (float*)d_out;
    float* z   = out;                       // [256]
    float* xg  = out + 256;                 // [256,512]
    float* xg1 = out + 256 + 256 * 512;     // [256,512]
    float* z1  = out + 256 + 2 * 256 * 512; // [256]

    char* wsb = (char*)d_ws;
    size_t off = 0;
    auto carve = [&](size_t bytes) {
        void* ptr = wsb + off;
        off = (off + bytes + 255) & ~(size_t)255;
        return ptr;
    };
    float* agg = (float*)carve((size_t)N1 * 93 * sizeof(float));   // also fc 'partial'
    float* h1  = (float*)carve((size_t)N1 * 93 * sizeof(float));   // also Wb1/Wb2/Wb3
    short* pb  = (short*)carve((size_t)NG * 2048 * sizeof(short));
    short* t1b = (short*)carve((size_t)NG * 1024 * sizeof(short));
    short* xgb = (short*)carve((size_t)NG * 512 * sizeof(short));
    float* t2  = (float*)carve((size_t)NG * 256 * sizeof(float));
    float* ppmax = (float*)carve((size_t)NG * 4 * 930 * sizeof(float));
    float* ppsum = (float*)carve((size_t)NG * 4 * 930 * sizeof(float));
    short* Wbg   = (short*)carve((size_t)59 * 16 * 96 * sizeof(short));
    int*   cnt    = (int*)carve(NG * sizeof(int));
    int*   offs   = (int*)carve((NG + 1) * sizeof(int));
    int*   deg    = (int*)carve((size_t)N1 * sizeof(int));
    int*   rowoff = (int*)carve((size_t)(N1 + 1) * sizeof(int));
    int*   cursor = (int*)carve((size_t)N1 * sizeof(int));
    int*   csr    = (int*)carve((size_t)E1 * sizeof(int));
    int*   bsum   = (int*)carve(128 * sizeof(int));

    // aliases into dead regions (stream-sequential safety):
    float* partial = agg;                       // fc partials (<= 8 MB <= 18.6 MB)
    short* Wb1 = (short*)h1;                    // 1024*2048*2 = 4 MB
    short* Wb2 = Wb1 + (size_t)1024 * 2048;     // 512*1024*2  = 1 MB
    short* Wb3 = Wb2 + (size_t)512 * 1024;      // 256*512*2   = 0.25 MB  (5.25 MB <= 18.6 MB)

    // branch 1: F=93, KPg=96, FO=930, NT=59; fc1 K=1860 -> KP1=2048
    run_branch<93, 96, 930, 59, 128, 2048>(x, ei, E1, N1, batch,
                                W1, b1, W2, b2,
                                fg_w1, fg_b1, fg_w2, fg_b2,
                                ff_w1, ff_b1, ff_w2, ff_b2,
                                agg, h1, pb, t1b, xgb, t2,
                                ppmax, ppsum, Wbg, Wb1, Wb2, Wb3, partial,
                                cnt, offs, deg, rowoff, cursor, csr, bsum,
                                xg, z, stream);

    // branch 2: F=43, KPg=64, FO=430, NT=27; fc1 K=860 -> KP1=1024
    run_branch<43, 64, 430, 27, 64, 1024>(a, ed, E2, N2, c,
                               W3, b3, W4, b4,
                               fg1_w1, fg1_b1, fg1_w2, fg1_b2,
                               ff1_w1, ff1_b1, ff1_w2, ff1_b2,
                               agg, h1, pb, t1b, xgb, t2,
                               ppmax, ppsum, Wbg, Wb1, Wb2, Wb3, partial,
                               cnt, offs, deg, rowoff, cursor, csr, bsum,
                               xg1, z1, stream);
}

// Round 6
// 861.831 us; speedup vs baseline: 1.1235x; 1.1235x over previous
//
#include <hip/hip_runtime.h>

// ---------------------------------------------------------------------------
// Round 6: kill hist_kernel (64us of same-address atomics on sorted batch ->
// 257-thread binary search); gin_linear -> bf16 MFMA; scan3 absorbs cursor
// copy. GIN2+pool MFMA and fc MFMA stack unchanged from R5.
// ---------------------------------------------------------------------------

static constexpr int NG = 256;  // number of graphs

typedef short  short8  __attribute__((ext_vector_type(8)));
typedef float  floatx4 __attribute__((ext_vector_type(4)));

__device__ __forceinline__ short f2bf(float f) {
    unsigned u = __float_as_uint(f);
    u += 0x7fff + ((u >> 16) & 1);          // RNE to bf16
    return (short)(u >> 16);
}

// ---- graph offsets via binary search (batch is sorted) --------------------
__global__ void offs_bsearch_kernel(const int* __restrict__ seg, int N,
                                    int* __restrict__ offs) {
    int g = blockIdx.x * blockDim.x + threadIdx.x;
    if (g > NG) return;
    int lo = 0, hi = N;                      // first idx with seg[idx] >= g
    while (lo < hi) {
        int mid = (lo + hi) >> 1;
        if (seg[mid] < g) lo = mid + 1; else hi = mid;
    }
    offs[g] = lo;
}

// ---- CSR build: histogram dst -> prefix scan -> fill ----------------------
__global__ void deg_kernel(const int* __restrict__ ei, int E, int* __restrict__ deg) {
    int e = blockIdx.x * blockDim.x + threadIdx.x;
    if (e < E) atomicAdd(&deg[ei[E + e]], 1);   // dst = ei[E+e]
}

__global__ __launch_bounds__(256) void scan1_kernel(const int* __restrict__ deg, int N,
                                                    int* __restrict__ excl,
                                                    int* __restrict__ bsum) {
    __shared__ int sh[256];
    int base = blockIdx.x * 1024;
    int t = threadIdx.x;
    int v[4];
    int s = 0;
    #pragma unroll
    for (int i = 0; i < 4; ++i) {
        int idx = base + t * 4 + i;
        v[i] = s;
        s += (idx < N) ? deg[idx] : 0;
    }
    sh[t] = s;
    __syncthreads();
    for (int off = 1; off < 256; off <<= 1) {
        int xv = (t >= off) ? sh[t - off] : 0;
        __syncthreads();
        sh[t] += xv;
        __syncthreads();
    }
    int texcl = (t > 0) ? sh[t - 1] : 0;
    #pragma unroll
    for (int i = 0; i < 4; ++i) {
        int idx = base + t * 4 + i;
        if (idx < N) excl[idx] = texcl + v[i];
    }
    if (t == 255) bsum[blockIdx.x] = sh[255];
}

__global__ void scan2_kernel(int* __restrict__ bsum, int nb) {
    if (threadIdx.x == 0) {
        int acc = 0;
        for (int i = 0; i < nb; ++i) { int t = bsum[i]; bsum[i] = acc; acc += t; }
    }
}

// adds block offsets AND writes the fill cursor (absorbs old copy_kernel)
__global__ void scan3_kernel(int* __restrict__ excl, const int* __restrict__ bsum,
                             int* __restrict__ cursor, int N, int E) {
    int i = blockIdx.x * blockDim.x + threadIdx.x;
    if (i < N) {
        int v = excl[i] + bsum[i >> 10];
        excl[i] = v;
        cursor[i] = v;
    }
    if (i == 0) excl[N] = E;
}

__global__ void fill_csr_kernel(const int* __restrict__ ei, int E,
                                int* __restrict__ cursor, int* __restrict__ csr) {
    int e = blockIdx.x * blockDim.x + threadIdx.x;
    if (e < E) {
        int dst = ei[E + e];
        int pos = atomicAdd(&cursor[dst], 1);
        csr[pos] = ei[e];                    // src
    }
}

// ---- gather: agg[n] = sum_{e: dst==n} x[src_e]  (wave per node) -----------
template<int F>
__global__ __launch_bounds__(256) void gather_kernel(const float* __restrict__ x,
        const int* __restrict__ csr, const int* __restrict__ ro,
        float* __restrict__ agg, int N) {
    int wave = (blockIdx.x * 256 + threadIdx.x) >> 6;
    int lane = threadIdx.x & 63;
    if (wave >= N) return;
    int s = ro[wave], e = ro[wave + 1];
    float a0 = 0.f, a1 = 0.f;
    const bool l0 = lane < F;
    const bool l1 = (lane + 64) < F;
    for (int i = s; i < e; ++i) {
        const float* row = x + (size_t)csr[i] * F;
        if (l0) a0 += row[lane];
        if (l1) a1 += row[lane + 64];
    }
    float* o = agg + (size_t)wave * F;
    if (l0) o[lane] = a0;
    if (l1) o[lane + 64] = a1;
}

// ---- W repack for MFMA B-fragments: W[F][FO] fp32 -> Wb[NT*16][KP] bf16 ---
template<int F, int KP, int FO, int NT>
__global__ void repack_w_kernel(const float* __restrict__ W, short* __restrict__ Wb) {
    int id = blockIdx.x * blockDim.x + threadIdx.x;   // col index incl. pad
    if (id >= NT * 16) return;
    for (int k = 0; k < KP; ++k) {
        float v = (k < F && id < FO) ? W[(size_t)k * FO + id] : 0.f;
        Wb[(size_t)id * KP + k] = f2bf(v);
    }
}

// ---- generic fc weight repack: W[K][N] fp32 -> Wb[N][KP] bf16 (zero-pad K)
__global__ __launch_bounds__(256) void repack_fc_kernel(
        const float* __restrict__ W, short* __restrict__ Wb,
        int K, int N, int KP) {
    int col = blockIdx.x * 256 + threadIdx.x;
    if (col >= N) return;
    int k0 = blockIdx.y * 64;
    int k1 = k0 + 64; if (k1 > KP) k1 = KP;
    for (int k = k0; k < k1; ++k) {
        float v = (k < K) ? W[(size_t)k * N + col] : 0.f;
        Wb[(size_t)col * KP + k] = f2bf(v);
    }
}

// ---- GIN layer 1, bf16 MFMA: out = relu((x+agg)@W + b), F -> F ------------
// block = 64 nodes; 4 waves stride the NT col-tiles; fp32 out (feeds gather).
template<int F, int KP, int NT>
__global__ __launch_bounds__(256) void gin_linear_mfma_kernel(
        const float* __restrict__ x, const float* __restrict__ agg,
        const short* __restrict__ Wb, const float* __restrict__ b,
        float* __restrict__ out, int N) {
    constexpr int KK = KP / 32;
    __shared__ __align__(16) short Vb[64][KP];
    int c0 = blockIdx.x * 64;
    int tid = threadIdx.x;
    int wid = tid >> 6;
    int lane = tid & 63;
    int ln = lane & 15, quad = lane >> 4;
    int cvalid = N - c0; if (cvalid > 64) cvalid = 64;
    for (int i = tid; i < 64 * (KP - F); i += 256)
        Vb[i / (KP - F)][F + i % (KP - F)] = 0;
    int nelem = cvalid * F;
    const float* xs = x + (size_t)c0 * F;
    const float* as = agg + (size_t)c0 * F;
    for (int idx = tid; idx < nelem; idx += 256)
        Vb[idx / F][idx % F] = f2bf(xs[idx] + as[idx]);
    __syncthreads();
    short8 afr[KK][4];
    #pragma unroll
    for (int kk = 0; kk < KK; ++kk)
        #pragma unroll
        for (int ms = 0; ms < 4; ++ms)
            afr[kk][ms] = *(const short8*)&Vb[ms * 16 + ln][kk * 32 + quad * 8];
    for (int nt = wid; nt < NT; nt += 4) {
        int col = nt * 16 + ln;
        float bcol = (col < F) ? b[col] : 0.f;
        short8 bfr[KK];
        const short8* bp = (const short8*)(Wb + (size_t)col * KP + quad * 8);
        #pragma unroll
        for (int kk = 0; kk < KK; ++kk) bfr[kk] = bp[kk * 4];
        #pragma unroll
        for (int ms = 0; ms < 4; ++ms) {
            if (ms * 16 < cvalid) {
                floatx4 acc = {0.f, 0.f, 0.f, 0.f};
                #pragma unroll
                for (int kk = 0; kk < KK; ++kk)
                    acc = __builtin_amdgcn_mfma_f32_16x16x32_bf16(
                              afr[kk][ms], bfr[kk], acc, 0, 0, 0);
                if (col < F) {
                    #pragma unroll
                    for (int r = 0; r < 4; ++r) {
                        int row = ms * 16 + quad * 4 + r;
                        if (row < cvalid)
                            out[(size_t)(c0 + row) * F + col] =
                                fmaxf(acc[r] + bcol, 0.f);
                    }
                }
            }
        }
    }
}

// ---- fused GIN layer 2 + pool, bf16 MFMA ----------------------------------
template<int F, int KP, int FO, int NT, int NS>
__global__ __launch_bounds__(256) void gin_pool_mfma_kernel(
        const float* __restrict__ h, const float* __restrict__ agg,
        const short* __restrict__ Wb, const float* __restrict__ b,
        const int* __restrict__ offs,
        float* __restrict__ ppmax, float* __restrict__ ppsum) {
    constexpr int KK = KP / 32;
    __shared__ __align__(16) short Vb[64][KP];
    __shared__ float pmaxL[NT * 16];
    __shared__ float psumL[NT * 16];
    int g = blockIdx.x / NS;
    int s = blockIdx.x % NS;
    int tid = threadIdx.x;
    int wid = tid >> 6;
    int lane = tid & 63;
    int ln = lane & 15;
    int quad = lane >> 4;

    int gs0 = offs[g], ge0 = offs[g + 1];
    int per = (ge0 - gs0 + NS - 1) / NS;
    int gs = gs0 + s * per;
    int ge = gs + per; if (ge > ge0) ge = ge0;

    for (int i = tid; i < NT * 16; i += 256) { pmaxL[i] = 0.f; psumL[i] = 0.f; }
    for (int i = tid; i < 64 * (KP - F); i += 256)
        Vb[i / (KP - F)][F + i % (KP - F)] = 0;

    for (int c0 = gs; c0 < ge; c0 += 64) {
        __syncthreads();
        int cvalid = ge - c0; if (cvalid > 64) cvalid = 64;
        int nelem = cvalid * F;
        const float* hs = h + (size_t)c0 * F;
        const float* as = agg + (size_t)c0 * F;
        for (int idx = tid; idx < nelem; idx += 256)
            Vb[idx / F][idx % F] = f2bf(hs[idx] + as[idx]);
        __syncthreads();
        short8 afr[KK][4];
        #pragma unroll
        for (int kk = 0; kk < KK; ++kk)
            #pragma unroll
            for (int ms = 0; ms < 4; ++ms)
                afr[kk][ms] = *(const short8*)&Vb[ms * 16 + ln][kk * 32 + quad * 8];
        for (int nt = wid; nt < NT; nt += 4) {
            int col = nt * 16 + ln;
            float bcol = (col < FO) ? b[col] : 0.f;
            short8 bfr[KK];
            const short8* bp = (const short8*)(Wb + (size_t)col * KP + quad * 8);
            #pragma unroll
            for (int kk = 0; kk < KK; ++kk) bfr[kk] = bp[kk * 4];
            float cmx = 0.f, csm = 0.f;
            #pragma unroll
            for (int ms = 0; ms < 4; ++ms) {
                if (ms * 16 < cvalid) {
                    floatx4 acc = {0.f, 0.f, 0.f, 0.f};
                    #pragma unroll
                    for (int kk = 0; kk < KK; ++kk)
                        acc = __builtin_amdgcn_mfma_f32_16x16x32_bf16(
                                  afr[kk][ms], bfr[kk], acc, 0, 0, 0);
                    #pragma unroll
                    for (int r = 0; r < 4; ++r) {
                        int rowl = ms * 16 + quad * 4 + r;
                        float v = fmaxf(acc[r] + bcol, 0.f);
                        if (rowl < cvalid) { cmx = fmaxf(cmx, v); csm += v; }
                    }
                }
            }
            cmx = fmaxf(cmx, __shfl_xor(cmx, 16, 64));
            cmx = fmaxf(cmx, __shfl_xor(cmx, 32, 64));
            csm += __shfl_xor(csm, 16, 64);
            csm += __shfl_xor(csm, 32, 64);
            if (quad == 0) {
                int i = nt * 16 + ln;
                pmaxL[i] = fmaxf(pmaxL[i], cmx);
                psumL[i] += csm;
            }
        }
    }
    __syncthreads();
    float* om = ppmax + (size_t)(g * NS + s) * FO;
    float* os = ppsum + (size_t)(g * NS + s) * FO;
    for (int col = tid; col < FO; col += 256) { om[col] = pmaxL[col]; os[col] = psumL[col]; }
}

// ---- combine partial pools -> pb bf16 [NG][KPAD]: [max | mean | 0-pad] ----
template<int FO, int NS, int KPAD>
__global__ __launch_bounds__(256) void pool_reduce_kernel(
        const float* __restrict__ ppmax, const float* __restrict__ ppsum,
        const int* __restrict__ offs, short* __restrict__ pb) {
    int g = blockIdx.x;
    int cntg = offs[g + 1] - offs[g];
    float den = (float)(cntg > 0 ? cntg : 1);
    for (int col = threadIdx.x; col < KPAD; col += 256) {
        float v = 0.f;
        if (col < FO) {
            float m = 0.f;
            #pragma unroll
            for (int ss = 0; ss < NS; ++ss)
                m = fmaxf(m, ppmax[(size_t)(g * NS + ss) * FO + col]);
            v = m;
        } else if (col < 2 * FO) {
            float sm = 0.f;
            #pragma unroll
            for (int ss = 0; ss < NS; ++ss)
                sm += ppsum[(size_t)(g * NS + ss) * FO + (col - FO)];
            v = sm / den;
        }
        pb[(size_t)g * KPAD + col] = f2bf(v);
    }
}

// ---- bf16 MFMA GEMM, split-K: partial[ks] = Ab[256,KP] @ Wb[N,KP]^T -------
template<int KPC>
__global__ __launch_bounds__(256) void fc_mfma_kernel(
        const short* __restrict__ Ab, const short* __restrict__ Wb,
        float* __restrict__ partial, int KP, int NB) {
    int bid = blockIdx.x;
    int mb = bid & 3;                 // M = 256 -> 4 row-tiles of 64
    int nb = (bid >> 2) % NB;
    int ks = (bid >> 2) / NB;
    int tid = threadIdx.x;
    int w = tid >> 6;
    int lane = tid & 63;
    int ln = lane & 15, quad = lane >> 4;
    int row = mb * 64 + w * 16 + ln;
    const short* ap = Ab + (size_t)row * KP + ks * KPC + quad * 8;
    const short* wp = Wb + (size_t)(nb * 64 + ln) * KP + ks * KPC + quad * 8;
    floatx4 acc[4];
    #pragma unroll
    for (int ns = 0; ns < 4; ++ns) acc[ns] = {0.f, 0.f, 0.f, 0.f};
    #pragma unroll
    for (int kk = 0; kk < KPC / 32; ++kk) {
        short8 a = *(const short8*)(ap + kk * 32);
        #pragma unroll
        for (int ns = 0; ns < 4; ++ns) {
            short8 b = *(const short8*)(wp + (size_t)ns * 16 * KP + kk * 32);
            acc[ns] = __builtin_amdgcn_mfma_f32_16x16x32_bf16(a, b, acc[ns], 0, 0, 0);
        }
    }
    int N = NB * 64;
    float* pp = partial + ((size_t)ks * 256 + mb * 64 + w * 16) * N + nb * 64;
    #pragma unroll
    for (int ns = 0; ns < 4; ++ns)
        #pragma unroll
        for (int r = 0; r < 4; ++r)
            pp[(quad * 4 + r) * N + ns * 16 + ln] = acc[ns][r];
}

// ---- split-K reduce: out = (relu?)(sum_ks partial + bias) -----------------
template<int KS, bool RELU, bool WBF16, bool WF32>
__global__ __launch_bounds__(256) void fc_reduce_kernel(
        const float* __restrict__ partial, const float* __restrict__ bias,
        short* __restrict__ outb, float* __restrict__ outf, int MN, int N) {
    int idx = blockIdx.x * 256 + threadIdx.x;
    if (idx >= MN) return;
    float v = bias[idx % N];
    #pragma unroll
    for (int s = 0; s < KS; ++s) v += partial[(size_t)s * MN + idx];
    if (RELU) v = fmaxf(v, 0.f);
    if (WBF16) outb[idx] = f2bf(v);
    if (WF32)  outf[idx] = v;
}

// ---- final head dot: z[row] = dot(t2[row,:256], w) + b[0] ------------------
__global__ __launch_bounds__(256) void final_dot_kernel(
        const float* __restrict__ A, const float* __restrict__ w,
        const float* __restrict__ b, float* __restrict__ z) {
    int row = blockIdx.x;
    int tid = threadIdx.x;
    float v = A[(size_t)row * 256 + tid] * w[tid];
    #pragma unroll
    for (int o = 32; o > 0; o >>= 1) v += __shfl_down(v, o, 64);
    __shared__ float red[4];
    if ((tid & 63) == 0) red[tid >> 6] = v;
    __syncthreads();
    if (tid == 0) z[row] = red[0] + red[1] + red[2] + red[3] + b[0];
}

// ---------------------------------------------------------------------------
static inline int cdiv(int a, int b) { return (a + b - 1) / b; }

template<int F, int KPg, int FO, int NT, int NTL, int KP1>
static void run_branch(const float* feat, const int* ei, int E, int N,
                       const int* seg,
                       const float* W1, const float* b1,
                       const float* W2, const float* b2,
                       const float* fw1, const float* fb1,
                       const float* fw2, const float* fb2,
                       const float* hw1, const float* hb1,
                       const float* hw2, const float* hb2,
                       float* agg, float* h1,
                       short* pb, short* t1b, short* xgb, float* t2,
                       float* ppmax, float* ppsum, short* Wbg, short* Wbl,
                       short* Wb1, short* Wb2, short* Wb3, float* partial,
                       int* offs, int* deg, int* rowoff, int* cursor,
                       int* csr, int* bsum,
                       float* xg_out, float* z_out, hipStream_t stream) {
    constexpr int NS = 4;
    constexpr int KS = 8;
    // graph segment offsets: binary search over sorted seg (no atomics)
    offs_bsearch_kernel<<<2, 256, 0, stream>>>(seg, N, offs);

    // CSR build
    hipMemsetAsync(deg, 0, N * sizeof(int), stream);
    deg_kernel<<<cdiv(E, 256), 256, 0, stream>>>(ei, E, deg);
    int nb = cdiv(N, 1024);
    scan1_kernel<<<nb, 256, 0, stream>>>(deg, N, rowoff, bsum);
    scan2_kernel<<<1, 64, 0, stream>>>(bsum, nb);
    scan3_kernel<<<cdiv(N, 256), 256, 0, stream>>>(rowoff, bsum, cursor, N, E);
    fill_csr_kernel<<<cdiv(E, 256), 256, 0, stream>>>(ei, E, cursor, csr);

    // weight repacks (GIN1, GIN2)
    repack_w_kernel<F, KPg, F, NTL><<<cdiv(NTL * 16, 64), 64, 0, stream>>>(W1, Wbl);
    repack_w_kernel<F, KPg, FO, NT><<<cdiv(NT * 16, 256), 256, 0, stream>>>(W2, Wbg);

    // GIN layer 1 (MFMA)
    gather_kernel<F><<<cdiv(N, 4), 256, 0, stream>>>(feat, csr, rowoff, agg, N);
    gin_linear_mfma_kernel<F, KPg, NTL><<<cdiv(N, 64), 256, 0, stream>>>(
        feat, agg, Wbl, b1, h1, N);

    // GIN layer 2 fused with pooling (MFMA)
    gather_kernel<F><<<cdiv(N, 4), 256, 0, stream>>>(h1, csr, rowoff, agg, N);
    gin_pool_mfma_kernel<F, KPg, FO, NT, NS><<<NG * NS, 256, 0, stream>>>(
        h1, agg, Wbg, b2, offs, ppmax, ppsum);

    // fc weight repacks (alias the h1 region -- h1 dead after gin_pool_mfma)
    {
        dim3 g1(cdiv(1024, 256), cdiv(KP1, 64));
        repack_fc_kernel<<<g1, 256, 0, stream>>>(fw1, Wb1, 2 * FO, 1024, KP1);
        dim3 g2(cdiv(512, 256), cdiv(1024, 64));
        repack_fc_kernel<<<g2, 256, 0, stream>>>(fw2, Wb2, 1024, 512, 1024);
        dim3 g3(cdiv(256, 256), cdiv(512, 64));
        repack_fc_kernel<<<g3, 256, 0, stream>>>(hw1, Wb3, 512, 256, 512);
    }

    // pool partials -> pb bf16 [256][KP1]
    pool_reduce_kernel<FO, NS, KP1><<<NG, 256, 0, stream>>>(ppmax, ppsum, offs, pb);

    // fc1: pb[256,KP1] @ Wb1 -> t1b[256,1024] (relu)
    fc_mfma_kernel<KP1 / KS><<<4 * 16 * KS, 256, 0, stream>>>(pb, Wb1, partial, KP1, 16);
    fc_reduce_kernel<KS, true, true, false><<<cdiv(256 * 1024, 256), 256, 0, stream>>>(
        partial, fb1, t1b, nullptr, 256 * 1024, 1024);

    // fc2: t1b[256,1024] @ Wb2 -> xg fp32 (output) + xgb bf16 (no relu)
    fc_mfma_kernel<1024 / KS><<<4 * 8 * KS, 256, 0, stream>>>(t1b, Wb2, partial, 1024, 8);
    fc_reduce_kernel<KS, false, true, true><<<cdiv(256 * 512, 256), 256, 0, stream>>>(
        partial, fb2, xgb, xg_out, 256 * 512, 512);

    // fc3 (head layer 1): xgb[256,512] @ Wb3 -> t2 fp32 [256,256] (relu)
    fc_mfma_kernel<512 / KS><<<4 * 4 * KS, 256, 0, stream>>>(xgb, Wb3, partial, 512, 4);
    fc_reduce_kernel<KS, true, false, true><<<cdiv(256 * 256, 256), 256, 0, stream>>>(
        partial, hb1, nullptr, t2, 256 * 256, 256);

    // final dot -> z
    final_dot_kernel<<<NG, 256, 0, stream>>>(t2, hw2, hb2, z_out);
}

extern "C" void kernel_launch(void* const* d_in, const int* in_sizes, int n_in,
                              void* d_out, int out_size, void* d_ws, size_t ws_size,
                              hipStream_t stream) {
    (void)n_in; (void)out_size; (void)ws_size;
    const float* x      = (const float*)d_in[1];
    const int*   ei     = (const int*)  d_in[2];
    const int*   batch  = (const int*)  d_in[3];
    const float* a      = (const float*)d_in[4];
    const int*   ed     = (const int*)  d_in[5];
    const int*   c      = (const int*)  d_in[6];
    const float* W1  = (const float*)d_in[7],  *b1  = (const float*)d_in[8];
    const float* W2  = (const float*)d_in[9],  *b2  = (const float*)d_in[10];
    const float* W3  = (const float*)d_in[11], *b3  = (const float*)d_in[12];
    const float* W4  = (const float*)d_in[13], *b4  = (const float*)d_in[14];
    const float* fg_w1  = (const float*)d_in[15], *fg_b1  = (const float*)d_in[16];
    const float* fg_w2  = (const float*)d_in[17], *fg_b2  = (const float*)d_in[18];
    const float* fg1_w1 = (const float*)d_in[19], *fg1_b1 = (const float*)d_in[20];
    const float* fg1_w2 = (const float*)d_in[21], *fg1_b2 = (const float*)d_in[22];
    const float* ff_w1  = (const float*)d_in[23], *ff_b1  = (const float*)d_in[24];
    const float* ff_w2  = (const float*)d_in[25], *ff_b2  = (const float*)d_in[26];
    const float* ff1_w1 = (const float*)d_in[27], *ff1_b1 = (const float*)d_in[28];
    const float* ff1_w2 = (const float*)d_in[29], *ff1_b2 = (const float*)d_in[30];

    const int N1 = in_sizes[1] / 93;
    const int E1 = in_sizes[2] / 2;
    const int N2 = in_sizes[4] / 43;
    const int E2 = in_sizes[5] / 2;

    float* out = (float*)d_out;
    float* z   = out;                       // [256]
    float* xg  = out + 256;                 // [256,512]
    float* xg1 = out + 256 + 256 * 512;     // [256,512]
    float* z1  = out + 256 + 2 * 256 * 512; // [256]

    char* wsb = (char*)d_ws;
    size_t off = 0;
    auto carve = [&](size_t bytes) {
        void* ptr = wsb + off;
        off = (off + bytes + 255) & ~(size_t)255;
        return ptr;
    };
    float* agg = (float*)carve((size_t)N1 * 93 * sizeof(float));   // also fc 'partial'
    float* h1  = (float*)carve((size_t)N1 * 93 * sizeof(float));   // also Wb1/Wb2/Wb3
    short* pb  = (short*)carve((size_t)NG * 2048 * sizeof(short));
    short* t1b = (short*)carve((size_t)NG * 1024 * sizeof(short));
    short* xgb = (short*)carve((size_t)NG * 512 * sizeof(short));
    float* t2  = (float*)carve((size_t)NG * 256 * sizeof(float));
    float* ppmax = (float*)carve((size_t)NG * 4 * 930 * sizeof(float));
    float* ppsum = (float*)carve((size_t)NG * 4 * 930 * sizeof(float));
    short* Wbg   = (short*)carve((size_t)59 * 16 * 96 * sizeof(short));
    short* Wbl   = (short*)carve((size_t)6 * 16 * 96 * sizeof(short));
    int*   offs   = (int*)carve((NG + 1) * sizeof(int));
    int*   deg    = (int*)carve((size_t)N1 * sizeof(int));
    int*   rowoff = (int*)carve((size_t)(N1 + 1) * sizeof(int));
    int*   cursor = (int*)carve((size_t)N1 * sizeof(int));
    int*   csr    = (int*)carve((size_t)E1 * sizeof(int));
    int*   bsum   = (int*)carve(128 * sizeof(int));

    // aliases into dead regions (stream-sequential safety):
    float* partial = agg;                       // fc partials (<= 8 MB <= 18.6 MB)
    short* Wb1 = (short*)h1;                    // 1024*2048*2 = 4 MB
    short* Wb2 = Wb1 + (size_t)1024 * 2048;     // 512*1024*2  = 1 MB
    short* Wb3 = Wb2 + (size_t)512 * 1024;      // 256*512*2   = 0.25 MB  (5.25 MB <= 18.6 MB)

    // branch 1: F=93, KPg=96, FO=930, NT=59, NTL=6; fc1 K=1860 -> KP1=2048
    run_branch<93, 96, 930, 59, 6, 2048>(x, ei, E1, N1, batch,
                                W1, b1, W2, b2,
                                fg_w1, fg_b1, fg_w2, fg_b2,
                                ff_w1, ff_b1, ff_w2, ff_b2,
                                agg, h1, pb, t1b, xgb, t2,
                                ppmax, ppsum, Wbg, Wbl, Wb1, Wb2, Wb3, partial,
                                offs, deg, rowoff, cursor, csr, bsum,
                                xg, z, stream);

    // branch 2: F=43, KPg=64, FO=430, NT=27, NTL=3; fc1 K=860 -> KP1=1024
    run_branch<43, 64, 430, 27, 3, 1024>(a, ed, E2, N2, c,
                               W3, b3, W4, b4,
                               fg1_w1, fg1_b1, fg1_w2, fg1_b2,
                               ff1_w1, ff1_b1, ff1_w2, ff1_b2,
                               agg, h1, pb, t1b, xgb, t2,
                               ppmax, ppsum, Wbg, Wbl, Wb1, Wb2, Wb3, partial,
                               offs, deg, rowoff, cursor, csr, bsum,
                               xg1, z1, stream);
}

// Round 7
// 600.309 us; speedup vs baseline: 1.6129x; 1.4356x over previous
//
#include <hip/hip_runtime.h>

// ---------------------------------------------------------------------------
// Round 7: bf16 rows for the random-access gathers (R6 profile: gather 53us,
// VALUBusy 9%, 101 MB L2-miss at 1.9 TB/s -> halve the bytes), launch-count
// reduction (one repack kernel for all 10 weights, CSR build batched across
// branches, fused head). MFMA GIN/FC machinery unchanged from R6.
// ---------------------------------------------------------------------------

static constexpr int NG = 256;  // number of graphs

typedef short  short8  __attribute__((ext_vector_type(8)));
typedef float  floatx4 __attribute__((ext_vector_type(4)));

__device__ __forceinline__ short f2bf(float f) {
    unsigned u = __float_as_uint(f);
    u += 0x7fff + ((u >> 16) & 1);          // RNE to bf16
    return (short)(u >> 16);
}
__device__ __forceinline__ float bf2f(unsigned short s) {
    return __uint_as_float((unsigned)s << 16);
}

// ---- graph offsets via binary search (batch sorted), both branches --------
__global__ void offs_both_kernel(const int* __restrict__ s1, int n1, int* __restrict__ o1,
                                 const int* __restrict__ s2, int n2, int* __restrict__ o2) {
    int t = blockIdx.x * 256 + threadIdx.x;
    int br = t >> 9;
    int g = t & 511;
    if (br > 1 || g > NG) return;
    const int* seg = br ? s2 : s1;
    int N = br ? n2 : n1;
    int* offs = br ? o2 : o1;
    int lo = 0, hi = N;
    while (lo < hi) {
        int mid = (lo + hi) >> 1;
        if (seg[mid] < g) lo = mid + 1; else hi = mid;
    }
    offs[g] = lo;
}

// ---- CSR build (both branches batched) ------------------------------------
__global__ void deg_both_kernel(const int* __restrict__ ei1, int E1, int* __restrict__ d1,
                                const int* __restrict__ ei2, int E2, int* __restrict__ d2) {
    int idx = blockIdx.x * 256 + threadIdx.x;
    if (idx < E1) atomicAdd(&d1[ei1[E1 + idx]], 1);
    else if (idx < E1 + E2) { int e = idx - E1; atomicAdd(&d2[ei2[E2 + e]], 1); }
}

__global__ __launch_bounds__(256) void scan1_both_kernel(
        const int* __restrict__ d1, int N1, int* __restrict__ x1, int* __restrict__ bs1, int nb1,
        const int* __restrict__ d2, int N2, int* __restrict__ x2, int* __restrict__ bs2) {
    __shared__ int sh[256];
    const int* deg; int* excl; int* bsum; int N; int blk;
    if ((int)blockIdx.x < nb1) { deg = d1; excl = x1; bsum = bs1; N = N1; blk = blockIdx.x; }
    else { deg = d2; excl = x2; bsum = bs2; N = N2; blk = blockIdx.x - nb1; }
    int base = blk * 1024;
    int t = threadIdx.x;
    int v[4];
    int s = 0;
    #pragma unroll
    for (int i = 0; i < 4; ++i) {
        int idx = base + t * 4 + i;
        v[i] = s;
        s += (idx < N) ? deg[idx] : 0;
    }
    sh[t] = s;
    __syncthreads();
    for (int off = 1; off < 256; off <<= 1) {
        int xv = (t >= off) ? sh[t - off] : 0;
        __syncthreads();
        sh[t] += xv;
        __syncthreads();
    }
    int texcl = (t > 0) ? sh[t - 1] : 0;
    #pragma unroll
    for (int i = 0; i < 4; ++i) {
        int idx = base + t * 4 + i;
        if (idx < N) excl[idx] = texcl + v[i];
    }
    if (t == 255) bsum[blk] = sh[255];
}

__global__ void scan2_both_kernel(int* __restrict__ b1, int nb1,
                                  int* __restrict__ b2, int nb2) {
    if (threadIdx.x) return;
    int* b = blockIdx.x ? b2 : b1;
    int nb = blockIdx.x ? nb2 : nb1;
    int acc = 0;
    for (int i = 0; i < nb; ++i) { int t = b[i]; b[i] = acc; acc += t; }
}

__global__ void scan3_both_kernel(int* __restrict__ x1, const int* __restrict__ bs1,
                                  int* __restrict__ c1, int N1, int Ev1,
                                  int* __restrict__ x2, const int* __restrict__ bs2,
                                  int* __restrict__ c2, int N2, int Ev2, int nc1) {
    int bid = blockIdx.x;
    int* excl; const int* bsum; int* cur; int N, E, i;
    if (bid < nc1) { i = bid * 256 + threadIdx.x; excl = x1; bsum = bs1; cur = c1; N = N1; E = Ev1; }
    else { i = (bid - nc1) * 256 + threadIdx.x; excl = x2; bsum = bs2; cur = c2; N = N2; E = Ev2; }
    if (i < N) {
        int v = excl[i] + bsum[i >> 10];
        excl[i] = v;
        cur[i] = v;
    }
    if (i == 0) excl[N] = E;
}

__global__ void fill_both_kernel(const int* __restrict__ ei1, int E1,
                                 int* __restrict__ c1, int* __restrict__ s1,
                                 const int* __restrict__ ei2, int E2,
                                 int* __restrict__ c2, int* __restrict__ s2) {
    int idx = blockIdx.x * 256 + threadIdx.x;
    if (idx < E1) {
        int pos = atomicAdd(&c1[ei1[E1 + idx]], 1);
        s1[pos] = ei1[idx];
    } else if (idx < E1 + E2) {
        int e = idx - E1;
        int pos = atomicAdd(&c2[ei2[E2 + e]], 1);
        s2[pos] = ei2[e];
    }
}

// ---- unified weight repack: W[K][Nsrc] fp32 -> Wb[Ndst][KP] bf16 ----------
struct RJob { const float* W; short* Wb; int K, Nsrc, Ndst, KP; };
struct RJobs10 { RJob j[10]; };

__global__ __launch_bounds__(256) void repack_all_kernel(RJobs10 jobs) {
    RJob jb = jobs.j[blockIdx.y];
    int colBlocks = (jb.Ndst + 255) >> 8;
    int cb = blockIdx.x;
    if (cb >= colBlocks * ((jb.KP + 63) >> 6)) return;
    int c = (cb % colBlocks) * 256 + threadIdx.x;
    if (c >= jb.Ndst) return;
    int k0 = (cb / colBlocks) * 64;
    int k1 = k0 + 64; if (k1 > jb.KP) k1 = jb.KP;
    for (int k = k0; k < k1; ++k) {
        float v = (k < jb.K && c < jb.Nsrc) ? jb.W[(size_t)k * jb.Nsrc + c] : 0.f;
        jb.Wb[(size_t)c * jb.KP + k] = f2bf(v);
    }
}

// ---- cast fp32 rows [N][F] -> bf16 padded rows [N][FP] --------------------
template<int F, int FP>
__global__ __launch_bounds__(256) void cast_rows_kernel(
        const float* __restrict__ x, unsigned short* __restrict__ xb, int N) {
    int idx = blockIdx.x * 256 + threadIdx.x;
    if (idx >= N * FP) return;
    int n = idx / FP;
    int k = idx - n * FP;
    float v = (k < F) ? x[(size_t)n * F + k] : 0.f;
    xb[idx] = (unsigned short)f2bf(v);
}

// ---- gather over bf16 rows: agg[n] = sum_{e: dst==n} xb[src_e] ------------
// wave per node; lane l covers features 2l,2l+1 (uint load); 2-edge unroll.
template<int F, int FP, int FA>
__global__ __launch_bounds__(256) void gather_b_kernel(
        const unsigned short* __restrict__ xb, const int* __restrict__ csr,
        const int* __restrict__ ro, float* __restrict__ agg, int N) {
    int wave = (blockIdx.x * 256 + threadIdx.x) >> 6;
    int lane = threadIdx.x & 63;
    if (wave >= N) return;
    constexpr int HW = FP / 2;
    const unsigned* base = (const unsigned*)xb;
    int s = ro[wave], e = ro[wave + 1];
    float lo = 0.f, hi = 0.f;
    bool act = lane < HW;
    int i = s;
    for (; i + 1 < e; i += 2) {
        int n0 = csr[i], n1 = csr[i + 1];
        unsigned u0 = act ? base[(size_t)n0 * HW + lane] : 0u;
        unsigned u1 = act ? base[(size_t)n1 * HW + lane] : 0u;
        lo += __uint_as_float(u0 << 16);
        hi += __uint_as_float(u0 & 0xffff0000u);
        lo += __uint_as_float(u1 << 16);
        hi += __uint_as_float(u1 & 0xffff0000u);
    }
    if (i < e) {
        int n0 = csr[i];
        unsigned u0 = act ? base[(size_t)n0 * HW + lane] : 0u;
        lo += __uint_as_float(u0 << 16);
        hi += __uint_as_float(u0 & 0xffff0000u);
    }
    int cidx = 2 * lane;
    if (cidx + 1 < F)
        *(float2*)&agg[(size_t)wave * FA + cidx] = make_float2(lo, hi);
    else if (cidx < F)
        agg[(size_t)wave * FA + cidx] = lo;
}

// ---- GIN layer 1, bf16 MFMA: h1b = relu((x+agg)@W + b), bf16 padded out ---
template<int F, int KP, int NT, int FP, int FA>
__global__ __launch_bounds__(256) void gin_linear_mfma_kernel(
        const float* __restrict__ x, const float* __restrict__ agg,
        const short* __restrict__ Wb, const float* __restrict__ b,
        unsigned short* __restrict__ h1b, int N) {
    constexpr int KK = KP / 32;
    __shared__ __align__(16) short Vb[64][KP];
    int c0 = blockIdx.x * 64;
    int tid = threadIdx.x;
    int wid = tid >> 6;
    int lane = tid & 63;
    int ln = lane & 15, quad = lane >> 4;
    int cvalid = N - c0; if (cvalid > 64) cvalid = 64;
    for (int i = tid; i < 64 * (KP - F); i += 256)
        Vb[i / (KP - F)][F + i % (KP - F)] = 0;
    int nelem = cvalid * F;
    const float* xs = x + (size_t)c0 * F;
    const float* as = agg + (size_t)c0 * FA;
    for (int idx = tid; idx < nelem; idx += 256) {
        int r = idx / F, k = idx - r * F;
        Vb[r][k] = f2bf(xs[idx] + as[r * FA + k]);
    }
    __syncthreads();
    short8 afr[KK][4];
    #pragma unroll
    for (int kk = 0; kk < KK; ++kk)
        #pragma unroll
        for (int ms = 0; ms < 4; ++ms)
            afr[kk][ms] = *(const short8*)&Vb[ms * 16 + ln][kk * 32 + quad * 8];
    for (int nt = wid; nt < NT; nt += 4) {
        int col = nt * 16 + ln;
        float bcol = (col < F) ? b[col] : 0.f;
        short8 bfr[KK];
        const short8* bp = (const short8*)(Wb + (size_t)col * KP + quad * 8);
        #pragma unroll
        for (int kk = 0; kk < KK; ++kk) bfr[kk] = bp[kk * 4];
        #pragma unroll
        for (int ms = 0; ms < 4; ++ms) {
            if (ms * 16 < cvalid) {
                floatx4 acc = {0.f, 0.f, 0.f, 0.f};
                #pragma unroll
                for (int kk = 0; kk < KK; ++kk)
                    acc = __builtin_amdgcn_mfma_f32_16x16x32_bf16(
                              afr[kk][ms], bfr[kk], acc, 0, 0, 0);
                #pragma unroll
                for (int r = 0; r < 4; ++r) {
                    int row = ms * 16 + quad * 4 + r;
                    if (row < cvalid) {
                        unsigned short hv = 0;
                        if (col < F) hv = (unsigned short)f2bf(fmaxf(acc[r] + bcol, 0.f));
                        h1b[(size_t)(c0 + row) * FP + col] = hv;
                    }
                }
            }
        }
    }
}

// ---- fused GIN layer 2 + pool, bf16 MFMA (h from bf16 rows + fp32 agg) ----
template<int F, int KP, int FO, int NT, int NS, int FP, int FA>
__global__ __launch_bounds__(256) void gin_pool_mfma_kernel(
        const unsigned short* __restrict__ h1b, const float* __restrict__ agg,
        const short* __restrict__ Wb, const float* __restrict__ b,
        const int* __restrict__ offs,
        float* __restrict__ ppmax, float* __restrict__ ppsum) {
    constexpr int KK = KP / 32;
    __shared__ __align__(16) short Vb[64][KP];
    __shared__ float pmaxL[NT * 16];
    __shared__ float psumL[NT * 16];
    int g = blockIdx.x / NS;
    int s = blockIdx.x % NS;
    int tid = threadIdx.x;
    int wid = tid >> 6;
    int lane = tid & 63;
    int ln = lane & 15;
    int quad = lane >> 4;

    int gs0 = offs[g], ge0 = offs[g + 1];
    int per = (ge0 - gs0 + NS - 1) / NS;
    int gs = gs0 + s * per;
    int ge = gs + per; if (ge > ge0) ge = ge0;

    for (int i = tid; i < NT * 16; i += 256) { pmaxL[i] = 0.f; psumL[i] = 0.f; }
    for (int i = tid; i < 64 * (KP - F); i += 256)
        Vb[i / (KP - F)][F + i % (KP - F)] = 0;

    for (int c0 = gs; c0 < ge; c0 += 64) {
        __syncthreads();
        int cvalid = ge - c0; if (cvalid > 64) cvalid = 64;
        int nelem = cvalid * F;
        const unsigned short* hs = h1b + (size_t)c0 * FP;
        const float* as = agg + (size_t)c0 * FA;
        for (int idx = tid; idx < nelem; idx += 256) {
            int r = idx / F, k = idx - r * F;
            Vb[r][k] = f2bf(bf2f(hs[r * FP + k]) + as[r * FA + k]);
        }
        __syncthreads();
        short8 afr[KK][4];
        #pragma unroll
        for (int kk = 0; kk < KK; ++kk)
            #pragma unroll
            for (int ms = 0; ms < 4; ++ms)
                afr[kk][ms] = *(const short8*)&Vb[ms * 16 + ln][kk * 32 + quad * 8];
        for (int nt = wid; nt < NT; nt += 4) {
            int col = nt * 16 + ln;
            float bcol = (col < FO) ? b[col] : 0.f;
            short8 bfr[KK];
            const short8* bp = (const short8*)(Wb + (size_t)col * KP + quad * 8);
            #pragma unroll
            for (int kk = 0; kk < KK; ++kk) bfr[kk] = bp[kk * 4];
            float cmx = 0.f, csm = 0.f;
            #pragma unroll
            for (int ms = 0; ms < 4; ++ms) {
                if (ms * 16 < cvalid) {
                    floatx4 acc = {0.f, 0.f, 0.f, 0.f};
                    #pragma unroll
                    for (int kk = 0; kk < KK; ++kk)
                        acc = __builtin_amdgcn_mfma_f32_16x16x32_bf16(
                                  afr[kk][ms], bfr[kk], acc, 0, 0, 0);
                    #pragma unroll
                    for (int r = 0; r < 4; ++r) {
                        int rowl = ms * 16 + quad * 4 + r;
                        float v = fmaxf(acc[r] + bcol, 0.f);
                        if (rowl < cvalid) { cmx = fmaxf(cmx, v); csm += v; }
                    }
                }
            }
            cmx = fmaxf(cmx, __shfl_xor(cmx, 16, 64));
            cmx = fmaxf(cmx, __shfl_xor(cmx, 32, 64));
            csm += __shfl_xor(csm, 16, 64);
            csm += __shfl_xor(csm, 32, 64);
            if (quad == 0) {
                int i = nt * 16 + ln;
                pmaxL[i] = fmaxf(pmaxL[i], cmx);
                psumL[i] += csm;
            }
        }
    }
    __syncthreads();
    float* om = ppmax + (size_t)(g * NS + s) * FO;
    float* os = ppsum + (size_t)(g * NS + s) * FO;
    for (int col = tid; col < FO; col += 256) { om[col] = pmaxL[col]; os[col] = psumL[col]; }
}

// ---- combine partial pools -> pb bf16 [NG][KPAD]: [max | mean | 0-pad] ----
template<int FO, int NS, int KPAD>
__global__ __launch_bounds__(256) void pool_reduce_kernel(
        const float* __restrict__ ppmax, const float* __restrict__ ppsum,
        const int* __restrict__ offs, short* __restrict__ pb) {
    int g = blockIdx.x;
    int cntg = offs[g + 1] - offs[g];
    float den = (float)(cntg > 0 ? cntg : 1);
    for (int col = threadIdx.x; col < KPAD; col += 256) {
        float v = 0.f;
        if (col < FO) {
            float m = 0.f;
            #pragma unroll
            for (int ss = 0; ss < NS; ++ss)
                m = fmaxf(m, ppmax[(size_t)(g * NS + ss) * FO + col]);
            v = m;
        } else if (col < 2 * FO) {
            float sm = 0.f;
            #pragma unroll
            for (int ss = 0; ss < NS; ++ss)
                sm += ppsum[(size_t)(g * NS + ss) * FO + (col - FO)];
            v = sm / den;
        }
        pb[(size_t)g * KPAD + col] = f2bf(v);
    }
}

// ---- bf16 MFMA GEMM, split-K: partial[ks] = Ab[256,KP] @ Wb[N,KP]^T -------
template<int KPC>
__global__ __launch_bounds__(256) void fc_mfma_kernel(
        const short* __restrict__ Ab, const short* __restrict__ Wb,
        float* __restrict__ partial, int KP, int NB) {
    int bid = blockIdx.x;
    int mb = bid & 3;                 // M = 256 -> 4 row-tiles of 64
    int nb = (bid >> 2) % NB;
    int ks = (bid >> 2) / NB;
    int tid = threadIdx.x;
    int w = tid >> 6;
    int lane = tid & 63;
    int ln = lane & 15, quad = lane >> 4;
    int row = mb * 64 + w * 16 + ln;
    const short* ap = Ab + (size_t)row * KP + ks * KPC + quad * 8;
    const short* wp = Wb + (size_t)(nb * 64 + ln) * KP + ks * KPC + quad * 8;
    floatx4 acc[4];
    #pragma unroll
    for (int ns = 0; ns < 4; ++ns) acc[ns] = {0.f, 0.f, 0.f, 0.f};
    #pragma unroll
    for (int kk = 0; kk < KPC / 32; ++kk) {
        short8 a = *(const short8*)(ap + kk * 32);
        #pragma unroll
        for (int ns = 0; ns < 4; ++ns) {
            short8 b = *(const short8*)(wp + (size_t)ns * 16 * KP + kk * 32);
            acc[ns] = __builtin_amdgcn_mfma_f32_16x16x32_bf16(a, b, acc[ns], 0, 0, 0);
        }
    }
    int N = NB * 64;
    float* pp = partial + ((size_t)ks * 256 + mb * 64 + w * 16) * N + nb * 64;
    #pragma unroll
    for (int ns = 0; ns < 4; ++ns)
        #pragma unroll
        for (int r = 0; r < 4; ++r)
            pp[(quad * 4 + r) * N + ns * 16 + ln] = acc[ns][r];
}

// ---- split-K reduce: out = (relu?)(sum_ks partial + bias) -----------------
template<int KS, bool RELU, bool WBF16, bool WF32>
__global__ __launch_bounds__(256) void fc_reduce_kernel(
        const float* __restrict__ partial, const float* __restrict__ bias,
        short* __restrict__ outb, float* __restrict__ outf, int MN, int N) {
    int idx = blockIdx.x * 256 + threadIdx.x;
    if (idx >= MN) return;
    float v = bias[idx % N];
    #pragma unroll
    for (int s = 0; s < KS; ++s) v += partial[(size_t)s * MN + idx];
    if (RELU) v = fmaxf(v, 0.f);
    if (WBF16) outb[idx] = f2bf(v);
    if (WF32)  outf[idx] = v;
}

// ---- fused head tail: z[row] = relu(sum partial + b1) . w2 + b2 -----------
template<int KS>
__global__ __launch_bounds__(256) void head_final_kernel(
        const float* __restrict__ partial, const float* __restrict__ b1v,
        const float* __restrict__ w2, const float* __restrict__ b2v,
        float* __restrict__ z) {
    int row = blockIdx.x;
    int t = threadIdx.x;
    float v = b1v[t];
    int idx = row * 256 + t;
    #pragma unroll
    for (int s = 0; s < KS; ++s) v += partial[(size_t)s * 65536 + idx];
    v = fmaxf(v, 0.f) * w2[t];
    #pragma unroll
    for (int o = 32; o > 0; o >>= 1) v += __shfl_down(v, o, 64);
    __shared__ float red[4];
    if ((t & 63) == 0) red[t >> 6] = v;
    __syncthreads();
    if (t == 0) z[row] = red[0] + red[1] + red[2] + red[3] + b2v[0];
}

// ---------------------------------------------------------------------------
static inline int cdiv(int a, int b) { return (a + b - 1) / b; }

// F: feat dim; KPg: MFMA staging K-pad; FO: GIN2 out; NT/NTL: col tiles;
// FP: bf16 row pad; FA: fp32 agg row pad; KP1: fc1 K-pad.
template<int F, int KPg, int FO, int NT, int NTL, int FP, int FA, int KP1>
static void run_branch(const float* feat, int E, int N,
                       const float* b1, const float* b2,
                       const float* fb1, const float* fb2,
                       const float* hb1, const float* hw2, const float* hb2,
                       float* agg, unsigned short* xb, unsigned short* h1b,
                       short* pb, short* t1b, short* xgb,
                       short* Wbl, short* Wbg, short* Wb1, short* Wb2, short* Wb3,
                       float* partial,
                       const int* offs, const int* rowoff, const int* csr,
                       float* xg_out, float* z_out, hipStream_t stream) {
    constexpr int NS = 4;
    constexpr int KS = 8;
    float* ppmax = (float*)xb;              // xb dead after gather2
    float* ppsum = ppmax + (size_t)NG * NS * FO;

    // cast input rows to bf16 (random-access table for gather1)
    cast_rows_kernel<F, FP><<<cdiv(N * FP, 256), 256, 0, stream>>>(feat, xb, N);

    // GIN layer 1
    gather_b_kernel<F, FP, FA><<<cdiv(N, 4), 256, 0, stream>>>(xb, csr, rowoff, agg, N);
    gin_linear_mfma_kernel<F, KPg, NTL, FP, FA><<<cdiv(N, 64), 256, 0, stream>>>(
        feat, agg, Wbl, b1, h1b, N);

    // GIN layer 2 fused with pooling
    gather_b_kernel<F, FP, FA><<<cdiv(N, 4), 256, 0, stream>>>(h1b, csr, rowoff, agg, N);
    gin_pool_mfma_kernel<F, KPg, FO, NT, NS, FP, FA><<<NG * NS, 256, 0, stream>>>(
        h1b, agg, Wbg, b2, offs, ppmax, ppsum);
    pool_reduce_kernel<FO, NS, KP1><<<NG, 256, 0, stream>>>(ppmax, ppsum, offs, pb);

    // FC stack (bf16 MFMA + split-K)
    fc_mfma_kernel<KP1 / KS><<<4 * 16 * KS, 256, 0, stream>>>(pb, Wb1, partial, KP1, 16);
    fc_reduce_kernel<KS, true, true, false><<<cdiv(256 * 1024, 256), 256, 0, stream>>>(
        partial, fb1, t1b, nullptr, 256 * 1024, 1024);
    fc_mfma_kernel<1024 / KS><<<4 * 8 * KS, 256, 0, stream>>>(t1b, Wb2, partial, 1024, 8);
    fc_reduce_kernel<KS, false, true, true><<<cdiv(256 * 512, 256), 256, 0, stream>>>(
        partial, fb2, xgb, xg_out, 256 * 512, 512);
    fc_mfma_kernel<512 / KS><<<4 * 4 * KS, 256, 0, stream>>>(xgb, Wb3, partial, 512, 4);
    head_final_kernel<KS><<<NG, 256, 0, stream>>>(partial, hb1, hw2, hb2, z_out);
}

extern "C" void kernel_launch(void* const* d_in, const int* in_sizes, int n_in,
                              void* d_out, int out_size, void* d_ws, size_t ws_size,
                              hipStream_t stream) {
    (void)n_in; (void)out_size; (void)ws_size;
    const float* x      = (const float*)d_in[1];
    const int*   ei     = (const int*)  d_in[2];
    const int*   batch  = (const int*)  d_in[3];
    const float* a      = (const float*)d_in[4];
    const int*   ed     = (const int*)  d_in[5];
    const int*   c      = (const int*)  d_in[6];
    const float* W1  = (const float*)d_in[7],  *b1  = (const float*)d_in[8];
    const float* W2  = (const float*)d_in[9],  *b2  = (const float*)d_in[10];
    const float* W3  = (const float*)d_in[11], *b3  = (const float*)d_in[12];
    const float* W4  = (const float*)d_in[13], *b4  = (const float*)d_in[14];
    const float* fg_w1  = (const float*)d_in[15], *fg_b1  = (const float*)d_in[16];
    const float* fg_w2  = (const float*)d_in[17], *fg_b2  = (const float*)d_in[18];
    const float* fg1_w1 = (const float*)d_in[19], *fg1_b1 = (const float*)d_in[20];
    const float* fg1_w2 = (const float*)d_in[21], *fg1_b2 = (const float*)d_in[22];
    const float* ff_w1  = (const float*)d_in[23], *ff_b1  = (const float*)d_in[24];
    const float* ff_w2  = (const float*)d_in[25], *ff_b2  = (const float*)d_in[26];
    const float* ff1_w1 = (const float*)d_in[27], *ff1_b1 = (const float*)d_in[28];
    const float* ff1_w2 = (const float*)d_in[29], *ff1_b2 = (const float*)d_in[30];

    const int N1 = in_sizes[1] / 93;
    const int E1 = in_sizes[2] / 2;
    const int N2 = in_sizes[4] / 43;
    const int E2 = in_sizes[5] / 2;

    float* out = (float*)d_out;
    float* z   = out;                       // [256]
    float* xg  = out + 256;                 // [256,512]
    float* xg1 = out + 256 + 256 * 512;     // [256,512]
    float* z1  = out + 256 + 2 * 256 * 512; // [256]

    char* wsb = (char*)d_ws;
    size_t off = 0;
    auto carve = [&](size_t bytes) {
        void* ptr = wsb + off;
        off = (off + bytes + 255) & ~(size_t)255;
        return ptr;
    };
    float*          agg  = (float*)carve((size_t)N1 * 94 * sizeof(float));  // FA-padded
    unsigned short* xb   = (unsigned short*)carve((size_t)N1 * 96 * 2);     // also ppmax/ppsum
    unsigned short* h1b  = (unsigned short*)carve((size_t)N1 * 96 * 2);
    short* pb  = (short*)carve((size_t)NG * 2048 * 2);
    short* t1b = (short*)carve((size_t)NG * 1024 * 2);
    short* xgb = (short*)carve((size_t)NG * 512 * 2);
    short* Wbl1 = (short*)carve((size_t)96 * 96 * 2);
    short* Wbg1 = (short*)carve((size_t)944 * 96 * 2);
    short* Wbl2 = (short*)carve((size_t)48 * 64 * 2);
    short* Wbg2 = (short*)carve((size_t)432 * 64 * 2);
    short* Wb1a = (short*)carve((size_t)1024 * 2048 * 2);
    short* Wb2a = (short*)carve((size_t)512 * 1024 * 2);
    short* Wb3a = (short*)carve((size_t)256 * 512 * 2);
    short* Wb1b = (short*)carve((size_t)1024 * 1024 * 2);
    short* Wb2b = (short*)carve((size_t)512 * 1024 * 2);
    short* Wb3b = (short*)carve((size_t)256 * 512 * 2);
    int* offs1 = (int*)carve(257 * 4);
    int* offs2 = (int*)carve(257 * 4);
    int* deg   = (int*)carve((size_t)(N1 + N2) * 4);
    int* rowoff1 = (int*)carve((size_t)(N1 + 1) * 4);
    int* rowoff2 = (int*)carve((size_t)(N2 + 1) * 4);
    int* cursor1 = (int*)carve((size_t)N1 * 4);
    int* cursor2 = (int*)carve((size_t)N2 * 4);
    int* csr1  = (int*)carve((size_t)E1 * 4);
    int* csr2  = (int*)carve((size_t)E2 * 4);
    int* bsum  = (int*)carve(256 * 4);
    int* deg1 = deg, *deg2 = deg + N1;
    int* bsum1 = bsum, *bsum2 = bsum + 128;
    float* partial = agg;                    // fc partials alias (agg dead by then)

    // ---- all 10 weight repacks in one launch -----------------------------
    RJobs10 jobs = {{
        { W1,     Wbl1, 93,   93,   96,   96   },
        { W2,     Wbg1, 93,   930,  944,  96   },
        { W3,     Wbl2, 43,   43,   48,   64   },
        { W4,     Wbg2, 43,   430,  432,  64   },
        { fg_w1,  Wb1a, 1860, 1024, 1024, 2048 },
        { fg_w2,  Wb2a, 1024, 512,  512,  1024 },
        { ff_w1,  Wb3a, 512,  256,  256,  512  },
        { fg1_w1, Wb1b, 860,  1024, 1024, 1024 },
        { fg1_w2, Wb2b, 1024, 512,  512,  1024 },
        { ff1_w1, Wb3b, 512,  256,  256,  512  },
    }};
    repack_all_kernel<<<dim3(128, 10), 256, 0, stream>>>(jobs);

    // ---- graph offsets + CSR build, both branches batched ----------------
    offs_both_kernel<<<4, 256, 0, stream>>>(batch, N1, offs1, c, N2, offs2);
    hipMemsetAsync(deg, 0, (size_t)(N1 + N2) * 4, stream);
    deg_both_kernel<<<cdiv(E1 + E2, 256), 256, 0, stream>>>(ei, E1, deg1, ed, E2, deg2);
    int nb1 = cdiv(N1, 1024), nb2 = cdiv(N2, 1024);
    scan1_both_kernel<<<nb1 + nb2, 256, 0, stream>>>(deg1, N1, rowoff1, bsum1, nb1,
                                                     deg2, N2, rowoff2, bsum2);
    scan2_both_kernel<<<2, 64, 0, stream>>>(bsum1, nb1, bsum2, nb2);
    int nc1 = cdiv(N1, 256), nc2 = cdiv(N2, 256);
    scan3_both_kernel<<<nc1 + nc2, 256, 0, stream>>>(rowoff1, bsum1, cursor1, N1, E1,
                                                     rowoff2, bsum2, cursor2, N2, E2, nc1);
    fill_both_kernel<<<cdiv(E1 + E2, 256), 256, 0, stream>>>(ei, E1, cursor1, csr1,
                                                             ed, E2, cursor2, csr2);

    // branch 1: F=93, KPg=96, FO=930, NT=59, NTL=6, FP=96, FA=94, KP1=2048
    run_branch<93, 96, 930, 59, 6, 96, 94, 2048>(
        x, E1, N1, b1, b2, fg_b1, fg_b2, ff_b1, ff_w2, ff_b2,
        agg, xb, h1b, pb, t1b, xgb,
        Wbl1, Wbg1, Wb1a, Wb2a, Wb3a, partial,
        offs1, rowoff1, csr1, xg, z, stream);

    // branch 2: F=43, KPg=64, FO=430, NT=27, NTL=3, FP=48, FA=44, KP1=1024
    run_branch<43, 64, 430, 27, 3, 48, 44, 1024>(
        a, E2, N2, b3, b4, fg1_b1, fg1_b2, ff1_b1, ff1_w2, ff1_b2,
        agg, xb, h1b, pb, t1b, xgb,
        Wbl2, Wbg2, Wb1b, Wb2b, Wb3b, partial,
        offs2, rowoff2, csr2, xg1, z1, stream);
}

// Round 8
// 510.095 us; speedup vs baseline: 1.8981x; 1.1769x over previous
//
#include <hip/hip_runtime.h>

// ---------------------------------------------------------------------------
// Round 8: LDS-tiled transpose weight repack (R7 profile: repack_all 110us --
// 2-byte stride-KP uncoalesced stores at 0.15 TB/s effective), merged casts,
// merged dual-branch FC stack (fewer launches, fuller grids).
// GIN chain (bf16 gathers + MFMA linear/pool) unchanged from R7.
// ---------------------------------------------------------------------------

static constexpr int NG = 256;  // number of graphs

typedef short  short8  __attribute__((ext_vector_type(8)));
typedef float  floatx4 __attribute__((ext_vector_type(4)));

__device__ __forceinline__ short f2bf(float f) {
    unsigned u = __float_as_uint(f);
    u += 0x7fff + ((u >> 16) & 1);          // RNE to bf16
    return (short)(u >> 16);
}
__device__ __forceinline__ float bf2f(unsigned short s) {
    return __uint_as_float((unsigned)s << 16);
}

// ---- graph offsets via binary search (batch sorted), both branches --------
__global__ void offs_both_kernel(const int* __restrict__ s1, int n1, int* __restrict__ o1,
                                 const int* __restrict__ s2, int n2, int* __restrict__ o2) {
    int t = blockIdx.x * 256 + threadIdx.x;
    int br = t >> 9;
    int g = t & 511;
    if (br > 1 || g > NG) return;
    const int* seg = br ? s2 : s1;
    int N = br ? n2 : n1;
    int* offs = br ? o2 : o1;
    int lo = 0, hi = N;
    while (lo < hi) {
        int mid = (lo + hi) >> 1;
        if (seg[mid] < g) lo = mid + 1; else hi = mid;
    }
    offs[g] = lo;
}

// ---- CSR build (both branches batched) ------------------------------------
__global__ void deg_both_kernel(const int* __restrict__ ei1, int E1, int* __restrict__ d1,
                                const int* __restrict__ ei2, int E2, int* __restrict__ d2) {
    int idx = blockIdx.x * 256 + threadIdx.x;
    if (idx < E1) atomicAdd(&d1[ei1[E1 + idx]], 1);
    else if (idx < E1 + E2) { int e = idx - E1; atomicAdd(&d2[ei2[E2 + e]], 1); }
}

__global__ __launch_bounds__(256) void scan1_both_kernel(
        const int* __restrict__ d1, int N1, int* __restrict__ x1, int* __restrict__ bs1, int nb1,
        const int* __restrict__ d2, int N2, int* __restrict__ x2, int* __restrict__ bs2) {
    __shared__ int sh[256];
    const int* deg; int* excl; int* bsum; int N; int blk;
    if ((int)blockIdx.x < nb1) { deg = d1; excl = x1; bsum = bs1; N = N1; blk = blockIdx.x; }
    else { deg = d2; excl = x2; bsum = bs2; N = N2; blk = blockIdx.x - nb1; }
    int base = blk * 1024;
    int t = threadIdx.x;
    int v[4];
    int s = 0;
    #pragma unroll
    for (int i = 0; i < 4; ++i) {
        int idx = base + t * 4 + i;
        v[i] = s;
        s += (idx < N) ? deg[idx] : 0;
    }
    sh[t] = s;
    __syncthreads();
    for (int off = 1; off < 256; off <<= 1) {
        int xv = (t >= off) ? sh[t - off] : 0;
        __syncthreads();
        sh[t] += xv;
        __syncthreads();
    }
    int texcl = (t > 0) ? sh[t - 1] : 0;
    #pragma unroll
    for (int i = 0; i < 4; ++i) {
        int idx = base + t * 4 + i;
        if (idx < N) excl[idx] = texcl + v[i];
    }
    if (t == 255) bsum[blk] = sh[255];
}

__global__ void scan2_both_kernel(int* __restrict__ b1, int nb1,
                                  int* __restrict__ b2, int nb2) {
    if (threadIdx.x) return;
    int* b = blockIdx.x ? b2 : b1;
    int nb = blockIdx.x ? nb2 : nb1;
    int acc = 0;
    for (int i = 0; i < nb; ++i) { int t = b[i]; b[i] = acc; acc += t; }
}

__global__ void scan3_both_kernel(int* __restrict__ x1, const int* __restrict__ bs1,
                                  int* __restrict__ c1, int N1, int Ev1,
                                  int* __restrict__ x2, const int* __restrict__ bs2,
                                  int* __restrict__ c2, int N2, int Ev2, int nc1) {
    int bid = blockIdx.x;
    int* excl; const int* bsum; int* cur; int N, E, i;
    if (bid < nc1) { i = bid * 256 + threadIdx.x; excl = x1; bsum = bs1; cur = c1; N = N1; E = Ev1; }
    else { i = (bid - nc1) * 256 + threadIdx.x; excl = x2; bsum = bs2; cur = c2; N = N2; E = Ev2; }
    if (i < N) {
        int v = excl[i] + bsum[i >> 10];
        excl[i] = v;
        cur[i] = v;
    }
    if (i == 0) excl[N] = E;
}

__global__ void fill_both_kernel(const int* __restrict__ ei1, int E1,
                                 int* __restrict__ c1, int* __restrict__ s1,
                                 const int* __restrict__ ei2, int E2,
                                 int* __restrict__ c2, int* __restrict__ s2) {
    int idx = blockIdx.x * 256 + threadIdx.x;
    if (idx < E1) {
        int pos = atomicAdd(&c1[ei1[E1 + idx]], 1);
        s1[pos] = ei1[idx];
    } else if (idx < E1 + E2) {
        int e = idx - E1;
        int pos = atomicAdd(&c2[ei2[E2 + e]], 1);
        s2[pos] = ei2[e];
    }
}

// ---- unified weight repack via LDS transpose tile -------------------------
// W[K][Nsrc] fp32 -> Wb[Ndst][KP] bf16. 64x64 tile: coalesced loads over c,
// coalesced uint4 (16B) stores over k (8 lanes = 128B contiguous).
struct RJob { const float* W; short* Wb; int K, Nsrc, Ndst, KP; };
struct RJobs10 { RJob j[10]; };

__global__ __launch_bounds__(256) void repack_all_kernel(RJobs10 jobs) {
    __shared__ __align__(16) short sh[64][72];
    RJob jb = jobs.j[blockIdx.y];
    int tilesC = (jb.Ndst + 63) >> 6;
    int tilesK = (jb.KP + 63) >> 6;
    if ((int)blockIdx.x >= tilesC * tilesK) return;
    int c0 = ((int)blockIdx.x % tilesC) * 64;
    int k0 = ((int)blockIdx.x / tilesC) * 64;
    int t = threadIdx.x;
    #pragma unroll 4
    for (int idx = t; idx < 64 * 64; idx += 256) {
        int kk = idx >> 6, cc = idx & 63;
        int k = k0 + kk, cg = c0 + cc;
        float v = (k < jb.K && cg < jb.Nsrc) ? jb.W[(size_t)k * jb.Nsrc + cg] : 0.f;
        sh[cc][kk] = f2bf(v);
    }
    __syncthreads();
    int kt = jb.KP - k0; if (kt > 64) kt = 64;
    int chunks = kt >> 3;                     // KP % 8 == 0 always
    for (int idx = t; idx < 64 * chunks; idx += 256) {
        int cc = idx / chunks, ch = idx - cc * chunks;
        int cg = c0 + cc;
        if (cg < jb.Ndst) {
            uint4 v = *(const uint4*)&sh[cc][ch * 8];
            *(uint4*)&jb.Wb[(size_t)cg * jb.KP + k0 + ch * 8] = v;
        }
    }
}

// ---- cast both inputs to bf16 padded rows ---------------------------------
__global__ __launch_bounds__(256) void cast_both_kernel(
        const float* __restrict__ x1, unsigned short* __restrict__ xb1, int N1,
        const float* __restrict__ x2, unsigned short* __restrict__ xb2, int N2) {
    int idx = blockIdx.x * 256 + threadIdx.x;
    int tot1 = N1 * 96;
    if (idx < tot1) {
        int n = idx / 96, k = idx - n * 96;
        float v = (k < 93) ? x1[(size_t)n * 93 + k] : 0.f;
        xb1[idx] = (unsigned short)f2bf(v);
    } else {
        idx -= tot1;
        if (idx < N2 * 48) {
            int n = idx / 48, k = idx - n * 48;
            float v = (k < 43) ? x2[(size_t)n * 43 + k] : 0.f;
            xb2[idx] = (unsigned short)f2bf(v);
        }
    }
}

// ---- gather over bf16 rows: agg[n] = sum_{e: dst==n} xb[src_e] ------------
template<int F, int FP, int FA>
__global__ __launch_bounds__(256) void gather_b_kernel(
        const unsigned short* __restrict__ xb, const int* __restrict__ csr,
        const int* __restrict__ ro, float* __restrict__ agg, int N) {
    int wave = (blockIdx.x * 256 + threadIdx.x) >> 6;
    int lane = threadIdx.x & 63;
    if (wave >= N) return;
    constexpr int HW = FP / 2;
    const unsigned* base = (const unsigned*)xb;
    int s = ro[wave], e = ro[wave + 1];
    float lo = 0.f, hi = 0.f;
    bool act = lane < HW;
    int i = s;
    for (; i + 1 < e; i += 2) {
        int n0 = csr[i], n1 = csr[i + 1];
        unsigned u0 = act ? base[(size_t)n0 * HW + lane] : 0u;
        unsigned u1 = act ? base[(size_t)n1 * HW + lane] : 0u;
        lo += __uint_as_float(u0 << 16);
        hi += __uint_as_float(u0 & 0xffff0000u);
        lo += __uint_as_float(u1 << 16);
        hi += __uint_as_float(u1 & 0xffff0000u);
    }
    if (i < e) {
        int n0 = csr[i];
        unsigned u0 = act ? base[(size_t)n0 * HW + lane] : 0u;
        lo += __uint_as_float(u0 << 16);
        hi += __uint_as_float(u0 & 0xffff0000u);
    }
    int cidx = 2 * lane;
    if (cidx + 1 < F)
        *(float2*)&agg[(size_t)wave * FA + cidx] = make_float2(lo, hi);
    else if (cidx < F)
        agg[(size_t)wave * FA + cidx] = lo;
}

// ---- GIN layer 1, bf16 MFMA: h1b = relu((x+agg)@W + b), bf16 padded out ---
template<int F, int KP, int NT, int FP, int FA>
__global__ __launch_bounds__(256) void gin_linear_mfma_kernel(
        const float* __restrict__ x, const float* __restrict__ agg,
        const short* __restrict__ Wb, const float* __restrict__ b,
        unsigned short* __restrict__ h1b, int N) {
    constexpr int KK = KP / 32;
    __shared__ __align__(16) short Vb[64][KP];
    int c0 = blockIdx.x * 64;
    int tid = threadIdx.x;
    int wid = tid >> 6;
    int lane = tid & 63;
    int ln = lane & 15, quad = lane >> 4;
    int cvalid = N - c0; if (cvalid > 64) cvalid = 64;
    for (int i = tid; i < 64 * (KP - F); i += 256)
        Vb[i / (KP - F)][F + i % (KP - F)] = 0;
    int nelem = cvalid * F;
    const float* xs = x + (size_t)c0 * F;
    const float* as = agg + (size_t)c0 * FA;
    for (int idx = tid; idx < nelem; idx += 256) {
        int r = idx / F, k = idx - r * F;
        Vb[r][k] = f2bf(xs[idx] + as[r * FA + k]);
    }
    __syncthreads();
    short8 afr[KK][4];
    #pragma unroll
    for (int kk = 0; kk < KK; ++kk)
        #pragma unroll
        for (int ms = 0; ms < 4; ++ms)
            afr[kk][ms] = *(const short8*)&Vb[ms * 16 + ln][kk * 32 + quad * 8];
    for (int nt = wid; nt < NT; nt += 4) {
        int col = nt * 16 + ln;
        float bcol = (col < F) ? b[col] : 0.f;
        short8 bfr[KK];
        const short8* bp = (const short8*)(Wb + (size_t)col * KP + quad * 8);
        #pragma unroll
        for (int kk = 0; kk < KK; ++kk) bfr[kk] = bp[kk * 4];
        #pragma unroll
        for (int ms = 0; ms < 4; ++ms) {
            if (ms * 16 < cvalid) {
                floatx4 acc = {0.f, 0.f, 0.f, 0.f};
                #pragma unroll
                for (int kk = 0; kk < KK; ++kk)
                    acc = __builtin_amdgcn_mfma_f32_16x16x32_bf16(
                              afr[kk][ms], bfr[kk], acc, 0, 0, 0);
                #pragma unroll
                for (int r = 0; r < 4; ++r) {
                    int row = ms * 16 + quad * 4 + r;
                    if (row < cvalid) {
                        unsigned short hv = 0;
                        if (col < F) hv = (unsigned short)f2bf(fmaxf(acc[r] + bcol, 0.f));
                        h1b[(size_t)(c0 + row) * FP + col] = hv;
                    }
                }
            }
        }
    }
}

// ---- fused GIN layer 2 + pool, bf16 MFMA ----------------------------------
template<int F, int KP, int FO, int NT, int NS, int FP, int FA>
__global__ __launch_bounds__(256) void gin_pool_mfma_kernel(
        const unsigned short* __restrict__ h1b, const float* __restrict__ agg,
        const short* __restrict__ Wb, const float* __restrict__ b,
        const int* __restrict__ offs,
        float* __restrict__ ppmax, float* __restrict__ ppsum) {
    constexpr int KK = KP / 32;
    __shared__ __align__(16) short Vb[64][KP];
    __shared__ float pmaxL[NT * 16];
    __shared__ float psumL[NT * 16];
    int g = blockIdx.x / NS;
    int s = blockIdx.x % NS;
    int tid = threadIdx.x;
    int wid = tid >> 6;
    int lane = tid & 63;
    int ln = lane & 15;
    int quad = lane >> 4;

    int gs0 = offs[g], ge0 = offs[g + 1];
    int per = (ge0 - gs0 + NS - 1) / NS;
    int gs = gs0 + s * per;
    int ge = gs + per; if (ge > ge0) ge = ge0;

    for (int i = tid; i < NT * 16; i += 256) { pmaxL[i] = 0.f; psumL[i] = 0.f; }
    for (int i = tid; i < 64 * (KP - F); i += 256)
        Vb[i / (KP - F)][F + i % (KP - F)] = 0;

    for (int c0 = gs; c0 < ge; c0 += 64) {
        __syncthreads();
        int cvalid = ge - c0; if (cvalid > 64) cvalid = 64;
        int nelem = cvalid * F;
        const unsigned short* hs = h1b + (size_t)c0 * FP;
        const float* as = agg + (size_t)c0 * FA;
        for (int idx = tid; idx < nelem; idx += 256) {
            int r = idx / F, k = idx - r * F;
            Vb[r][k] = f2bf(bf2f(hs[r * FP + k]) + as[r * FA + k]);
        }
        __syncthreads();
        short8 afr[KK][4];
        #pragma unroll
        for (int kk = 0; kk < KK; ++kk)
            #pragma unroll
            for (int ms = 0; ms < 4; ++ms)
                afr[kk][ms] = *(const short8*)&Vb[ms * 16 + ln][kk * 32 + quad * 8];
        for (int nt = wid; nt < NT; nt += 4) {
            int col = nt * 16 + ln;
            float bcol = (col < FO) ? b[col] : 0.f;
            short8 bfr[KK];
            const short8* bp = (const short8*)(Wb + (size_t)col * KP + quad * 8);
            #pragma unroll
            for (int kk = 0; kk < KK; ++kk) bfr[kk] = bp[kk * 4];
            float cmx = 0.f, csm = 0.f;
            #pragma unroll
            for (int ms = 0; ms < 4; ++ms) {
                if (ms * 16 < cvalid) {
                    floatx4 acc = {0.f, 0.f, 0.f, 0.f};
                    #pragma unroll
                    for (int kk = 0; kk < KK; ++kk)
                        acc = __builtin_amdgcn_mfma_f32_16x16x32_bf16(
                                  afr[kk][ms], bfr[kk], acc, 0, 0, 0);
                    #pragma unroll
                    for (int r = 0; r < 4; ++r) {
                        int rowl = ms * 16 + quad * 4 + r;
                        float v = fmaxf(acc[r] + bcol, 0.f);
                        if (rowl < cvalid) { cmx = fmaxf(cmx, v); csm += v; }
                    }
                }
            }
            cmx = fmaxf(cmx, __shfl_xor(cmx, 16, 64));
            cmx = fmaxf(cmx, __shfl_xor(cmx, 32, 64));
            csm += __shfl_xor(csm, 16, 64);
            csm += __shfl_xor(csm, 32, 64);
            if (quad == 0) {
                int i = nt * 16 + ln;
                pmaxL[i] = fmaxf(pmaxL[i], cmx);
                psumL[i] += csm;
            }
        }
    }
    __syncthreads();
    float* om = ppmax + (size_t)(g * NS + s) * FO;
    float* os = ppsum + (size_t)(g * NS + s) * FO;
    for (int col = tid; col < FO; col += 256) { om[col] = pmaxL[col]; os[col] = psumL[col]; }
}

// ---- combine partial pools -> pb bf16 [NG][KPAD]: [max | mean | 0-pad] ----
template<int FO, int NS, int KPAD>
__global__ __launch_bounds__(256) void pool_reduce_kernel(
        const float* __restrict__ ppmax, const float* __restrict__ ppsum,
        const int* __restrict__ offs, short* __restrict__ pb) {
    int g = blockIdx.x;
    int cntg = offs[g + 1] - offs[g];
    float den = (float)(cntg > 0 ? cntg : 1);
    for (int col = threadIdx.x; col < KPAD; col += 256) {
        float v = 0.f;
        if (col < FO) {
            float m = 0.f;
            #pragma unroll
            for (int ss = 0; ss < NS; ++ss)
                m = fmaxf(m, ppmax[(size_t)(g * NS + ss) * FO + col]);
            v = m;
        } else if (col < 2 * FO) {
            float sm = 0.f;
            #pragma unroll
            for (int ss = 0; ss < NS; ++ss)
                sm += ppsum[(size_t)(g * NS + ss) * FO + (col - FO)];
            v = sm / den;
        }
        pb[(size_t)g * KPAD + col] = f2bf(v);
    }
}

// ---- bf16 MFMA GEMM device body, split-K ----------------------------------
template<int KPC>
__device__ __forceinline__ void fc_mfma_dev(
        const short* __restrict__ Ab, const short* __restrict__ Wb,
        float* __restrict__ partial, int KP, int NB, int bid) {
    int mb = bid & 3;                 // M = 256 -> 4 row-tiles of 64
    int nb = (bid >> 2) % NB;
    int ks = (bid >> 2) / NB;
    int tid = threadIdx.x;
    int w = tid >> 6;
    int lane = tid & 63;
    int ln = lane & 15, quad = lane >> 4;
    int row = mb * 64 + w * 16 + ln;
    const short* ap = Ab + (size_t)row * KP + ks * KPC + quad * 8;
    const short* wp = Wb + (size_t)(nb * 64 + ln) * KP + ks * KPC + quad * 8;
    floatx4 acc[4];
    #pragma unroll
    for (int ns = 0; ns < 4; ++ns) acc[ns] = {0.f, 0.f, 0.f, 0.f};
    #pragma unroll
    for (int kk = 0; kk < KPC / 32; ++kk) {
        short8 a = *(const short8*)(ap + kk * 32);
        #pragma unroll
        for (int ns = 0; ns < 4; ++ns) {
            short8 b = *(const short8*)(wp + (size_t)ns * 16 * KP + kk * 32);
            acc[ns] = __builtin_amdgcn_mfma_f32_16x16x32_bf16(a, b, acc[ns], 0, 0, 0);
        }
    }
    int N = NB * 64;
    float* pp = partial + ((size_t)ks * 256 + mb * 64 + w * 16) * N + nb * 64;
    #pragma unroll
    for (int ns = 0; ns < 4; ++ns)
        #pragma unroll
        for (int r = 0; r < 4; ++r)
            pp[(quad * 4 + r) * N + ns * 16 + ln] = acc[ns][r];
}

template<int KPC1, int KPC2>
__global__ __launch_bounds__(256) void fc_mfma_both_kernel(
        const short* A1, const short* B1, float* P1, int KPa, int NBa, int nblk1,
        const short* A2, const short* B2, float* P2, int KPb, int NBb) {
    int bid = blockIdx.x;
    if (bid < nblk1) fc_mfma_dev<KPC1>(A1, B1, P1, KPa, NBa, bid);
    else             fc_mfma_dev<KPC2>(A2, B2, P2, KPb, NBb, bid - nblk1);
}

// ---- split-K reduce (both branches): out = (relu?)(sum partial + bias) ----
template<int KS, bool RELU, bool WBF16, bool WF32>
__global__ __launch_bounds__(256) void fc_reduce_both_kernel(
        const float* __restrict__ P1, const float* __restrict__ b1v,
        short* __restrict__ ob1, float* __restrict__ of1, int MN1, int Nn1,
        const float* __restrict__ P2, const float* __restrict__ b2v,
        short* __restrict__ ob2, float* __restrict__ of2, int MN2, int Nn2) {
    int idx = blockIdx.x * 256 + threadIdx.x;
    const float* P; const float* bias; short* ob; float* of; int MN, Nn;
    if (idx < MN1) { P = P1; bias = b1v; ob = ob1; of = of1; MN = MN1; Nn = Nn1; }
    else {
        idx -= MN1;
        if (idx >= MN2) return;
        P = P2; bias = b2v; ob = ob2; of = of2; MN = MN2; Nn = Nn2;
    }
    float v = bias[idx % Nn];
    #pragma unroll
    for (int s = 0; s < KS; ++s) v += P[(size_t)s * MN + idx];
    if (RELU) v = fmaxf(v, 0.f);
    if (WBF16) ob[idx] = f2bf(v);
    if (WF32)  of[idx] = v;
}

// ---- fused head tail (both): z[row] = relu(sum partial + b1) . w2 + b2 ----
template<int KS>
__global__ __launch_bounds__(256) void head_final_both_kernel(
        const float* __restrict__ P1, const float* __restrict__ b11,
        const float* __restrict__ w21, const float* __restrict__ b21,
        float* __restrict__ z1o,
        const float* __restrict__ P2, const float* __restrict__ b12,
        const float* __restrict__ w22, const float* __restrict__ b22,
        float* __restrict__ z2o) {
    int br = blockIdx.x >> 8;
    int row = blockIdx.x & 255;
    const float* P  = br ? P2  : P1;
    const float* b1 = br ? b12 : b11;
    const float* w2 = br ? w22 : w21;
    const float* b2 = br ? b22 : b21;
    float* zo       = br ? z2o : z1o;
    int t = threadIdx.x;
    float v = b1[t];
    int idx = row * 256 + t;
    #pragma unroll
    for (int s = 0; s < KS; ++s) v += P[(size_t)s * 65536 + idx];
    v = fmaxf(v, 0.f) * w2[t];
    #pragma unroll
    for (int o = 32; o > 0; o >>= 1) v += __shfl_down(v, o, 64);
    __shared__ float red[4];
    if ((t & 63) == 0) red[t >> 6] = v;
    __syncthreads();
    if (t == 0) zo[row] = red[0] + red[1] + red[2] + red[3] + b2[0];
}

// ---------------------------------------------------------------------------
static inline int cdiv(int a, int b) { return (a + b - 1) / b; }

// GIN chain for one branch (FC stack handled merged, afterwards).
template<int F, int KPg, int FO, int NT, int NTL, int FP, int FA, int KP1>
static void run_gin(const float* feat, int N,
                    const float* b1, const float* b2,
                    float* agg, unsigned short* xb, unsigned short* h1b, short* pb,
                    const short* Wbl, const short* Wbg,
                    const int* offs, const int* rowoff, const int* csr,
                    hipStream_t stream) {
    constexpr int NS = 4;
    float* ppmax = (float*)xb;              // xb dead after gather1
    float* ppsum = ppmax + (size_t)NG * NS * FO;

    gather_b_kernel<F, FP, FA><<<cdiv(N, 4), 256, 0, stream>>>(xb, csr, rowoff, agg, N);
    gin_linear_mfma_kernel<F, KPg, NTL, FP, FA><<<cdiv(N, 64), 256, 0, stream>>>(
        feat, agg, Wbl, b1, h1b, N);
    gather_b_kernel<F, FP, FA><<<cdiv(N, 4), 256, 0, stream>>>(h1b, csr, rowoff, agg, N);
    gin_pool_mfma_kernel<F, KPg, FO, NT, NS, FP, FA><<<NG * NS, 256, 0, stream>>>(
        h1b, agg, Wbg, b2, offs, ppmax, ppsum);
    pool_reduce_kernel<FO, NS, KP1><<<NG, 256, 0, stream>>>(ppmax, ppsum, offs, pb);
}

extern "C" void kernel_launch(void* const* d_in, const int* in_sizes, int n_in,
                              void* d_out, int out_size, void* d_ws, size_t ws_size,
                              hipStream_t stream) {
    (void)n_in; (void)out_size; (void)ws_size;
    const float* x      = (const float*)d_in[1];
    const int*   ei     = (const int*)  d_in[2];
    const int*   batch  = (const int*)  d_in[3];
    const float* a      = (const float*)d_in[4];
    const int*   ed     = (const int*)  d_in[5];
    const int*   c      = (const int*)  d_in[6];
    const float* W1  = (const float*)d_in[7],  *b1  = (const float*)d_in[8];
    const float* W2  = (const float*)d_in[9],  *b2  = (const float*)d_in[10];
    const float* W3  = (const float*)d_in[11], *b3  = (const float*)d_in[12];
    const float* W4  = (const float*)d_in[13], *b4  = (const float*)d_in[14];
    const float* fg_w1  = (const float*)d_in[15], *fg_b1  = (const float*)d_in[16];
    const float* fg_w2  = (const float*)d_in[17], *fg_b2  = (const float*)d_in[18];
    const float* fg1_w1 = (const float*)d_in[19], *fg1_b1 = (const float*)d_in[20];
    const float* fg1_w2 = (const float*)d_in[21], *fg1_b2 = (const float*)d_in[22];
    const float* ff_w1  = (const float*)d_in[23], *ff_b1  = (const float*)d_in[24];
    const float* ff_w2  = (const float*)d_in[25], *ff_b2  = (const float*)d_in[26];
    const float* ff1_w1 = (const float*)d_in[27], *ff1_b1 = (const float*)d_in[28];
    const float* ff1_w2 = (const float*)d_in[29], *ff1_b2 = (const float*)d_in[30];

    const int N1 = in_sizes[1] / 93;
    const int E1 = in_sizes[2] / 2;
    const int N2 = in_sizes[4] / 43;
    const int E2 = in_sizes[5] / 2;

    float* out = (float*)d_out;
    float* z   = out;                       // [256]
    float* xg  = out + 256;                 // [256,512]
    float* xg1 = out + 256 + 256 * 512;     // [256,512]
    float* z1  = out + 256 + 2 * 256 * 512; // [256]

    char* wsb = (char*)d_ws;
    size_t off = 0;
    auto carve = [&](size_t bytes) {
        void* ptr = wsb + off;
        off = (off + bytes + 255) & ~(size_t)255;
        return ptr;
    };
    float*          agg  = (float*)carve((size_t)N1 * 94 * sizeof(float));  // shared; also partials
    unsigned short* xb1  = (unsigned short*)carve((size_t)N1 * 96 * 2);     // also ppmax/ppsum b1
    unsigned short* xb2  = (unsigned short*)carve((size_t)N2 * 48 * 2);     // also ppmax/ppsum b2
    unsigned short* h1b  = (unsigned short*)carve((size_t)N1 * 96 * 2);     // shared across branches
    short* pb1  = (short*)carve((size_t)NG * 2048 * 2);
    short* pb2  = (short*)carve((size_t)NG * 1024 * 2);
    short* t1b1 = (short*)carve((size_t)NG * 1024 * 2);
    short* t1b2 = (short*)carve((size_t)NG * 1024 * 2);
    short* xgb1 = (short*)carve((size_t)NG * 512 * 2);
    short* xgb2 = (short*)carve((size_t)NG * 512 * 2);
    short* Wbl1 = (short*)carve((size_t)96 * 96 * 2);
    short* Wbg1 = (short*)carve((size_t)944 * 96 * 2);
    short* Wbl2 = (short*)carve((size_t)48 * 64 * 2);
    short* Wbg2 = (short*)carve((size_t)432 * 64 * 2);
    short* Wb1a = (short*)carve((size_t)1024 * 2048 * 2);
    short* Wb2a = (short*)carve((size_t)512 * 1024 * 2);
    short* Wb3a = (short*)carve((size_t)256 * 512 * 2);
    short* Wb1b = (short*)carve((size_t)1024 * 1024 * 2);
    short* Wb2b = (short*)carve((size_t)512 * 1024 * 2);
    short* Wb3b = (short*)carve((size_t)256 * 512 * 2);
    int* offs1 = (int*)carve(257 * 4);
    int* offs2 = (int*)carve(257 * 4);
    int* deg   = (int*)carve((size_t)(N1 + N2) * 4);
    int* rowoff1 = (int*)carve((size_t)(N1 + 1) * 4);
    int* rowoff2 = (int*)carve((size_t)(N2 + 1) * 4);
    int* cursor1 = (int*)carve((size_t)N1 * 4);
    int* cursor2 = (int*)carve((size_t)N2 * 4);
    int* csr1  = (int*)carve((size_t)E1 * 4);
    int* csr2  = (int*)carve((size_t)E2 * 4);
    int* bsum  = (int*)carve(256 * 4);
    int* deg1 = deg, *deg2 = deg + N1;
    int* bsum1 = bsum, *bsum2 = bsum + 128;
    // fc partials alias agg (agg dead after both GIN chains): 8 MB + 8 MB <= 18.8 MB
    float* partial1 = agg;
    float* partial2 = agg + (size_t)8 * 262144;   // 8 MB offset in floats

    constexpr int KS = 8;

    // ---- prologue: weight repacks (LDS transpose), casts, CSR build ------
    RJobs10 jobs = {{
        { W1,     Wbl1, 93,   93,   96,   96   },
        { W2,     Wbg1, 93,   930,  944,  96   },
        { W3,     Wbl2, 43,   43,   48,   64   },
        { W4,     Wbg2, 43,   430,  432,  64   },
        { fg_w1,  Wb1a, 1860, 1024, 1024, 2048 },
        { fg_w2,  Wb2a, 1024, 512,  512,  1024 },
        { ff_w1,  Wb3a, 512,  256,  256,  512  },
        { fg1_w1, Wb1b, 860,  1024, 1024, 1024 },
        { fg1_w2, Wb2b, 1024, 512,  512,  1024 },
        { ff1_w1, Wb3b, 512,  256,  256,  512  },
    }};
    repack_all_kernel<<<dim3(512, 10), 256, 0, stream>>>(jobs);
    cast_both_kernel<<<cdiv(N1 * 96 + N2 * 48, 256), 256, 0, stream>>>(
        x, xb1, N1, a, xb2, N2);
    offs_both_kernel<<<4, 256, 0, stream>>>(batch, N1, offs1, c, N2, offs2);
    hipMemsetAsync(deg, 0, (size_t)(N1 + N2) * 4, stream);
    deg_both_kernel<<<cdiv(E1 + E2, 256), 256, 0, stream>>>(ei, E1, deg1, ed, E2, deg2);
    int nb1 = cdiv(N1, 1024), nb2 = cdiv(N2, 1024);
    scan1_both_kernel<<<nb1 + nb2, 256, 0, stream>>>(deg1, N1, rowoff1, bsum1, nb1,
                                                     deg2, N2, rowoff2, bsum2);
    scan2_both_kernel<<<2, 64, 0, stream>>>(bsum1, nb1, bsum2, nb2);
    int nc1 = cdiv(N1, 256), nc2 = cdiv(N2, 256);
    scan3_both_kernel<<<nc1 + nc2, 256, 0, stream>>>(rowoff1, bsum1, cursor1, N1, E1,
                                                     rowoff2, bsum2, cursor2, N2, E2, nc1);
    fill_both_kernel<<<cdiv(E1 + E2, 256), 256, 0, stream>>>(ei, E1, cursor1, csr1,
                                                             ed, E2, cursor2, csr2);

    // ---- GIN chains (sequential; share agg/h1b) --------------------------
    run_gin<93, 96, 930, 59, 6, 96, 94, 2048>(x, N1, b1, b2,
        agg, xb1, h1b, pb1, Wbl1, Wbg1, offs1, rowoff1, csr1, stream);
    run_gin<43, 64, 430, 27, 3, 48, 44, 1024>(a, N2, b3, b4,
        agg, xb2, h1b, pb2, Wbl2, Wbg2, offs2, rowoff2, csr2, stream);

    // ---- merged FC stack (both branches per launch) ----------------------
    // fc1: pb @ Wb1 -> t1b (relu);  b1: KP=2048 KPC=256, b2: KP=1024 KPC=128
    fc_mfma_both_kernel<256, 128><<<1024, 256, 0, stream>>>(
        pb1, Wb1a, partial1, 2048, 16, 512, pb2, Wb1b, partial2, 1024, 16);
    fc_reduce_both_kernel<KS, true, true, false><<<cdiv(2 * 256 * 1024, 256), 256, 0, stream>>>(
        partial1, fg_b1, t1b1, nullptr, 256 * 1024, 1024,
        partial2, fg1_b1, t1b2, nullptr, 256 * 1024, 1024);
    // fc2: t1b @ Wb2 -> xg fp32 (output) + xgb bf16
    fc_mfma_both_kernel<128, 128><<<512, 256, 0, stream>>>(
        t1b1, Wb2a, partial1, 1024, 8, 256, t1b2, Wb2b, partial2, 1024, 8);
    fc_reduce_both_kernel<KS, false, true, true><<<cdiv(2 * 256 * 512, 256), 256, 0, stream>>>(
        partial1, fg_b2, xgb1, xg, 256 * 512, 512,
        partial2, fg1_b2, xgb2, xg1, 256 * 512, 512);
    // fc3: xgb @ Wb3 -> partial; head folds reduce+relu+dot
    fc_mfma_both_kernel<64, 64><<<256, 256, 0, stream>>>(
        xgb1, Wb3a, partial1, 512, 4, 128, xgb2, Wb3b, partial2, 512, 4);
    head_final_both_kernel<KS><<<512, 256, 0, stream>>>(
        partial1, ff_b1, ff_w2, ff_b2, z,
        partial2, ff1_b1, ff1_w2, ff1_b2, z1);
}

// Round 9
// 451.226 us; speedup vs baseline: 2.1458x; 1.1305x over previous
//
#include <hip/hip_runtime.h>

// ---------------------------------------------------------------------------
// Round 9: windowed XCD-affine CSR build (R8: fill 54us, WRITE_SIZE 45MB for a
// 3.2MB array -- cross-XCD partial-line writebacks; window=blockIdx%8 pins each
// dst-range to one XCD), merged dual-branch GIN chain (5 fewer launches),
// gather ILP (4-edge unroll b1; 2 lane-groups b2). FC stack unchanged.
// ---------------------------------------------------------------------------

static constexpr int NG  = 256;   // graphs
static constexpr int CHK = 4096;  // edges per (chunk,window) block

typedef short  short8  __attribute__((ext_vector_type(8)));
typedef float  floatx4 __attribute__((ext_vector_type(4)));

__device__ __forceinline__ short f2bf(float f) {
    unsigned u = __float_as_uint(f);
    u += 0x7fff + ((u >> 16) & 1);          // RNE to bf16
    return (short)(u >> 16);
}
__device__ __forceinline__ float bf2f(unsigned short s) {
    return __uint_as_float((unsigned)s << 16);
}
__device__ __forceinline__ float bf_lo(unsigned u) { return __uint_as_float(u << 16); }
__device__ __forceinline__ float bf_hi(unsigned u) { return __uint_as_float(u & 0xffff0000u); }

static inline int cdiv(int a, int b) { return (a + b - 1) / b; }

// ---- graph offsets via binary search (batch sorted), both branches --------
__global__ void offs_both_kernel(const int* __restrict__ s1, int n1, int* __restrict__ o1,
                                 const int* __restrict__ s2, int n2, int* __restrict__ o2) {
    int t = blockIdx.x * 256 + threadIdx.x;
    int br = t >> 9;
    int g = t & 511;
    if (br > 1 || g > NG) return;
    const int* seg = br ? s2 : s1;
    int N = br ? n2 : n1;
    int* offs = br ? o2 : o1;
    int lo = 0, hi = N;
    while (lo < hi) {
        int mid = (lo + hi) >> 1;
        if (seg[mid] < g) lo = mid + 1; else hi = mid;
    }
    offs[g] = lo;
}

// ---- windowed degree histogram (XCD-affine: window = bid & 7) -------------
__device__ __forceinline__ void deg_win_dev(const int* __restrict__ ei, int E, int N,
                                            int* __restrict__ deg, int bid) {
    int win = bid & 7, chunk = bid >> 3;
    int e0 = chunk * CHK;
    int e1 = e0 + CHK; if (e1 > E) e1 = E;
    int wlo = (int)((long)win * N / 8);
    int whi = (int)((long)(win + 1) * N / 8);
    for (int e = e0 + threadIdx.x; e < e1; e += 256) {
        int dst = ei[E + e];
        if (dst >= wlo && dst < whi) atomicAdd(&deg[dst], 1);
    }
}

__global__ __launch_bounds__(256) void deg_win_both_kernel(
        const int* ei1, int E1, int N1, int* d1, int nblk1,
        const int* ei2, int E2, int N2, int* d2) {
    int bid = blockIdx.x;
    if (bid < nblk1) deg_win_dev(ei1, E1, N1, d1, bid);
    else             deg_win_dev(ei2, E2, N2, d2, bid - nblk1);
}

// ---- prefix scans (unchanged) ---------------------------------------------
__global__ __launch_bounds__(256) void scan1_both_kernel(
        const int* __restrict__ d1, int N1, int* __restrict__ x1, int* __restrict__ bs1, int nb1,
        const int* __restrict__ d2, int N2, int* __restrict__ x2, int* __restrict__ bs2) {
    __shared__ int sh[256];
    const int* deg; int* excl; int* bsum; int N; int blk;
    if ((int)blockIdx.x < nb1) { deg = d1; excl = x1; bsum = bs1; N = N1; blk = blockIdx.x; }
    else { deg = d2; excl = x2; bsum = bs2; N = N2; blk = blockIdx.x - nb1; }
    int base = blk * 1024;
    int t = threadIdx.x;
    int v[4];
    int s = 0;
    #pragma unroll
    for (int i = 0; i < 4; ++i) {
        int idx = base + t * 4 + i;
        v[i] = s;
        s += (idx < N) ? deg[idx] : 0;
    }
    sh[t] = s;
    __syncthreads();
    for (int off = 1; off < 256; off <<= 1) {
        int xv = (t >= off) ? sh[t - off] : 0;
        __syncthreads();
        sh[t] += xv;
        __syncthreads();
    }
    int texcl = (t > 0) ? sh[t - 1] : 0;
    #pragma unroll
    for (int i = 0; i < 4; ++i) {
        int idx = base + t * 4 + i;
        if (idx < N) excl[idx] = texcl + v[i];
    }
    if (t == 255) bsum[blk] = sh[255];
}

__global__ void scan2_both_kernel(int* __restrict__ b1, int nb1,
                                  int* __restrict__ b2, int nb2) {
    if (threadIdx.x) return;
    int* b = blockIdx.x ? b2 : b1;
    int nb = blockIdx.x ? nb2 : nb1;
    int acc = 0;
    for (int i = 0; i < nb; ++i) { int t = b[i]; b[i] = acc; acc += t; }
}

__global__ void scan3_both_kernel(int* __restrict__ x1, const int* __restrict__ bs1,
                                  int* __restrict__ c1, int N1, int Ev1,
                                  int* __restrict__ x2, const int* __restrict__ bs2,
                                  int* __restrict__ c2, int N2, int Ev2, int nc1) {
    int bid = blockIdx.x;
    int* excl; const int* bsum; int* cur; int N, E, i;
    if (bid < nc1) { i = bid * 256 + threadIdx.x; excl = x1; bsum = bs1; cur = c1; N = N1; E = Ev1; }
    else { i = (bid - nc1) * 256 + threadIdx.x; excl = x2; bsum = bs2; cur = c2; N = N2; E = Ev2; }
    if (i < N) {
        int v = excl[i] + bsum[i >> 10];
        excl[i] = v;
        cur[i] = v;
    }
    if (i == 0) excl[N] = E;
}

// ---- windowed CSR fill (XCD-affine) ---------------------------------------
__device__ __forceinline__ void fill_win_dev(const int* __restrict__ ei, int E, int N,
                                             int* __restrict__ cursor, int* __restrict__ csr,
                                             int bid) {
    int win = bid & 7, chunk = bid >> 3;
    int e0 = chunk * CHK;
    int e1 = e0 + CHK; if (e1 > E) e1 = E;
    int wlo = (int)((long)win * N / 8);
    int whi = (int)((long)(win + 1) * N / 8);
    for (int e = e0 + threadIdx.x; e < e1; e += 256) {
        int dst = ei[E + e];
        if (dst >= wlo && dst < whi) {
            int pos = atomicAdd(&cursor[dst], 1);
            csr[pos] = ei[e];
        }
    }
}

__global__ __launch_bounds__(256) void fill_win_both_kernel(
        const int* ei1, int E1, int N1, int* c1, int* s1, int nblk1,
        const int* ei2, int E2, int N2, int* c2, int* s2) {
    int bid = blockIdx.x;
    if (bid < nblk1) fill_win_dev(ei1, E1, N1, c1, s1, bid);
    else             fill_win_dev(ei2, E2, N2, c2, s2, bid - nblk1);
}

// ---- unified weight repack via LDS transpose tile -------------------------
struct RJob { const float* W; short* Wb; int K, Nsrc, Ndst, KP; };
struct RJobs10 { RJob j[10]; };

__global__ __launch_bounds__(256) void repack_all_kernel(RJobs10 jobs) {
    __shared__ __align__(16) short sh[64][72];
    RJob jb = jobs.j[blockIdx.y];
    int tilesC = (jb.Ndst + 63) >> 6;
    int tilesK = (jb.KP + 63) >> 6;
    if ((int)blockIdx.x >= tilesC * tilesK) return;
    int c0 = ((int)blockIdx.x % tilesC) * 64;
    int k0 = ((int)blockIdx.x / tilesC) * 64;
    int t = threadIdx.x;
    #pragma unroll 4
    for (int idx = t; idx < 64 * 64; idx += 256) {
        int kk = idx >> 6, cc = idx & 63;
        int k = k0 + kk, cg = c0 + cc;
        float v = (k < jb.K && cg < jb.Nsrc) ? jb.W[(size_t)k * jb.Nsrc + cg] : 0.f;
        sh[cc][kk] = f2bf(v);
    }
    __syncthreads();
    int kt = jb.KP - k0; if (kt > 64) kt = 64;
    int chunks = kt >> 3;
    for (int idx = t; idx < 64 * chunks; idx += 256) {
        int cc = idx / chunks, ch = idx - cc * chunks;
        int cg = c0 + cc;
        if (cg < jb.Ndst) {
            uint4 v = *(const uint4*)&sh[cc][ch * 8];
            *(uint4*)&jb.Wb[(size_t)cg * jb.KP + k0 + ch * 8] = v;
        }
    }
}

// ---- cast both inputs to bf16 padded rows ---------------------------------
__global__ __launch_bounds__(256) void cast_both_kernel(
        const float* __restrict__ x1, unsigned short* __restrict__ xb1, int N1,
        const float* __restrict__ x2, unsigned short* __restrict__ xb2, int N2) {
    int idx = blockIdx.x * 256 + threadIdx.x;
    int tot1 = N1 * 96;
    if (idx < tot1) {
        int n = idx / 96, k = idx - n * 96;
        float v = (k < 93) ? x1[(size_t)n * 93 + k] : 0.f;
        xb1[idx] = (unsigned short)f2bf(v);
    } else {
        idx -= tot1;
        if (idx < N2 * 48) {
            int n = idx / 48, k = idx - n * 48;
            float v = (k < 43) ? x2[(size_t)n * 43 + k] : 0.f;
            xb2[idx] = (unsigned short)f2bf(v);
        }
    }
}

// ---- gather over bf16 rows (device body) ----------------------------------
// GROUPS=1: one 64-lane group, 4-edge unroll. GROUPS=2: two 32-lane groups
// each 2-edge unrolled, combined via shfl_xor(32).
template<int F, int FP, int FA, int GROUPS>
__device__ __forceinline__ void gather_dev(
        const unsigned short* __restrict__ xb, const int* __restrict__ csr,
        const int* __restrict__ ro, float* __restrict__ agg, int N, int bid) {
    int wave = (bid * 256 + threadIdx.x) >> 6;
    int lane = threadIdx.x & 63;
    if (wave >= N) return;
    constexpr int HW = FP / 2;
    const unsigned* base = (const unsigned*)xb;
    int s = ro[wave], e = ro[wave + 1];
    int grp, l;
    if (GROUPS == 2) { grp = lane >> 5; l = lane & 31; }
    else             { grp = 0;         l = lane;      }
    bool act = l < HW;
    float lo = 0.f, hi = 0.f;
    int i = s + grp;
    if (GROUPS == 1) {
        for (; i + 3 < e; i += 4) {
            int n0 = csr[i], n1 = csr[i + 1], n2 = csr[i + 2], n3 = csr[i + 3];
            unsigned u0 = act ? base[(size_t)n0 * HW + l] : 0u;
            unsigned u1 = act ? base[(size_t)n1 * HW + l] : 0u;
            unsigned u2 = act ? base[(size_t)n2 * HW + l] : 0u;
            unsigned u3 = act ? base[(size_t)n3 * HW + l] : 0u;
            lo += bf_lo(u0) + bf_lo(u1) + bf_lo(u2) + bf_lo(u3);
            hi += bf_hi(u0) + bf_hi(u1) + bf_hi(u2) + bf_hi(u3);
        }
        for (; i < e; ++i) {
            int n0 = csr[i];
            unsigned u0 = act ? base[(size_t)n0 * HW + l] : 0u;
            lo += bf_lo(u0); hi += bf_hi(u0);
        }
    } else {
        for (; i + 2 < e; i += 4) {            // per group: edges i, i+2
            int n0 = csr[i], n1 = csr[i + 2];
            unsigned u0 = act ? base[(size_t)n0 * HW + l] : 0u;
            unsigned u1 = act ? base[(size_t)n1 * HW + l] : 0u;
            lo += bf_lo(u0) + bf_lo(u1);
            hi += bf_hi(u0) + bf_hi(u1);
        }
        if (i < e) {
            int n0 = csr[i];
            unsigned u0 = act ? base[(size_t)n0 * HW + l] : 0u;
            lo += bf_lo(u0); hi += bf_hi(u0);
        }
        lo += __shfl_xor(lo, 32, 64);
        hi += __shfl_xor(hi, 32, 64);
    }
    if (grp == 0) {
        int cidx = 2 * l;
        if (cidx + 1 < F)
            *(float2*)&agg[(size_t)wave * FA + cidx] = make_float2(lo, hi);
        else if (cidx < F)
            agg[(size_t)wave * FA + cidx] = lo;
    }
}

__global__ __launch_bounds__(256) void gather_both_kernel(
        const unsigned short* xb1, const int* csr1, const int* ro1, float* agg1, int N1, int nblk1,
        const unsigned short* xb2, const int* csr2, const int* ro2, float* agg2, int N2) {
    int bid = blockIdx.x;
    if (bid < nblk1) gather_dev<93, 96, 94, 1>(xb1, csr1, ro1, agg1, N1, bid);
    else             gather_dev<43, 48, 44, 2>(xb2, csr2, ro2, agg2, N2, bid - nblk1);
}

// ---- GIN layer 1 MFMA (device body, flat LDS) -----------------------------
template<int F, int KP, int NT, int FP, int FA>
__device__ __forceinline__ void gin_linear_dev(
        const float* __restrict__ x, const float* __restrict__ agg,
        const short* __restrict__ Wb, const float* __restrict__ b,
        unsigned short* __restrict__ h1b, int N, int blk, short* Vb) {
    constexpr int KK = KP / 32;
    int c0 = blk * 64;
    int tid = threadIdx.x;
    int wid = tid >> 6;
    int lane = tid & 63;
    int ln = lane & 15, quad = lane >> 4;
    int cvalid = N - c0; if (cvalid > 64) cvalid = 64;
    for (int i = tid; i < 64 * (KP - F); i += 256)
        Vb[(i / (KP - F)) * KP + F + i % (KP - F)] = 0;
    int nelem = cvalid * F;
    const float* xs = x + (size_t)c0 * F;
    const float* as = agg + (size_t)c0 * FA;
    for (int idx = tid; idx < nelem; idx += 256) {
        int r = idx / F, k = idx - r * F;
        Vb[r * KP + k] = f2bf(xs[idx] + as[r * FA + k]);
    }
    __syncthreads();
    short8 afr[KK][4];
    #pragma unroll
    for (int kk = 0; kk < KK; ++kk)
        #pragma unroll
        for (int ms = 0; ms < 4; ++ms)
            afr[kk][ms] = *(const short8*)&Vb[(ms * 16 + ln) * KP + kk * 32 + quad * 8];
    for (int nt = wid; nt < NT; nt += 4) {
        int col = nt * 16 + ln;
        float bcol = (col < F) ? b[col] : 0.f;
        short8 bfr[KK];
        const short8* bp = (const short8*)(Wb + (size_t)col * KP + quad * 8);
        #pragma unroll
        for (int kk = 0; kk < KK; ++kk) bfr[kk] = bp[kk * 4];
        #pragma unroll
        for (int ms = 0; ms < 4; ++ms) {
            if (ms * 16 < cvalid) {
                floatx4 acc = {0.f, 0.f, 0.f, 0.f};
                #pragma unroll
                for (int kk = 0; kk < KK; ++kk)
                    acc = __builtin_amdgcn_mfma_f32_16x16x32_bf16(
                              afr[kk][ms], bfr[kk], acc, 0, 0, 0);
                #pragma unroll
                for (int r = 0; r < 4; ++r) {
                    int row = ms * 16 + quad * 4 + r;
                    if (row < cvalid) {
                        unsigned short hv = 0;
                        if (col < F) hv = (unsigned short)f2bf(fmaxf(acc[r] + bcol, 0.f));
                        h1b[(size_t)(c0 + row) * FP + col] = hv;
                    }
                }
            }
        }
    }
}

__global__ __launch_bounds__(256) void gin_linear_both_kernel(
        const float* x1, const float* agg1, const short* Wbl1, const float* bb1,
        unsigned short* h1b1, int N1, int nblk1,
        const float* x2, const float* agg2, const short* Wbl2, const float* bb2,
        unsigned short* h1b2, int N2) {
    __shared__ __align__(16) short Vb[64 * 96];
    int bid = blockIdx.x;
    if (bid < nblk1)
        gin_linear_dev<93, 96, 6, 96, 94>(x1, agg1, Wbl1, bb1, h1b1, N1, bid, Vb);
    else
        gin_linear_dev<43, 64, 3, 48, 44>(x2, agg2, Wbl2, bb2, h1b2, N2, bid - nblk1, Vb);
}

// ---- fused GIN layer 2 + pool MFMA (device body, flat LDS) ----------------
template<int F, int KP, int FO, int NT, int NS, int FP, int FA>
__device__ __forceinline__ void gin_pool_dev(
        const unsigned short* __restrict__ h1b, const float* __restrict__ agg,
        const short* __restrict__ Wb, const float* __restrict__ b,
        const int* __restrict__ offs,
        float* __restrict__ ppmax, float* __restrict__ ppsum,
        int blk, short* Vb, float* pmaxL, float* psumL) {
    constexpr int KK = KP / 32;
    int g = blk / NS;
    int s = blk % NS;
    int tid = threadIdx.x;
    int wid = tid >> 6;
    int lane = tid & 63;
    int ln = lane & 15;
    int quad = lane >> 4;

    int gs0 = offs[g], ge0 = offs[g + 1];
    int per = (ge0 - gs0 + NS - 1) / NS;
    int gs = gs0 + s * per;
    int ge = gs + per; if (ge > ge0) ge = ge0;

    for (int i = tid; i < NT * 16; i += 256) { pmaxL[i] = 0.f; psumL[i] = 0.f; }
    for (int i = tid; i < 64 * (KP - F); i += 256)
        Vb[(i / (KP - F)) * KP + F + i % (KP - F)] = 0;

    for (int c0 = gs; c0 < ge; c0 += 64) {
        __syncthreads();
        int cvalid = ge - c0; if (cvalid > 64) cvalid = 64;
        int nelem = cvalid * F;
        const unsigned short* hs = h1b + (size_t)c0 * FP;
        const float* as = agg + (size_t)c0 * FA;
        for (int idx = tid; idx < nelem; idx += 256) {
            int r = idx / F, k = idx - r * F;
            Vb[r * KP + k] = f2bf(bf2f(hs[r * FP + k]) + as[r * FA + k]);
        }
        __syncthreads();
        short8 afr[KK][4];
        #pragma unroll
        for (int kk = 0; kk < KK; ++kk)
            #pragma unroll
            for (int ms = 0; ms < 4; ++ms)
                afr[kk][ms] = *(const short8*)&Vb[(ms * 16 + ln) * KP + kk * 32 + quad * 8];
        for (int nt = wid; nt < NT; nt += 4) {
            int col = nt * 16 + ln;
            float bcol = (col < FO) ? b[col] : 0.f;
            short8 bfr[KK];
            const short8* bp = (const short8*)(Wb + (size_t)col * KP + quad * 8);
            #pragma unroll
            for (int kk = 0; kk < KK; ++kk) bfr[kk] = bp[kk * 4];
            float cmx = 0.f, csm = 0.f;
            #pragma unroll
            for (int ms = 0; ms < 4; ++ms) {
                if (ms * 16 < cvalid) {
                    floatx4 acc = {0.f, 0.f, 0.f, 0.f};
                    #pragma unroll
                    for (int kk = 0; kk < KK; ++kk)
                        acc = __builtin_amdgcn_mfma_f32_16x16x32_bf16(
                                  afr[kk][ms], bfr[kk], acc, 0, 0, 0);
                    #pragma unroll
                    for (int r = 0; r < 4; ++r) {
                        int rowl = ms * 16 + quad * 4 + r;
                        float v = fmaxf(acc[r] + bcol, 0.f);
                        if (rowl < cvalid) { cmx = fmaxf(cmx, v); csm += v; }
                    }
                }
            }
            cmx = fmaxf(cmx, __shfl_xor(cmx, 16, 64));
            cmx = fmaxf(cmx, __shfl_xor(cmx, 32, 64));
            csm += __shfl_xor(csm, 16, 64);
            csm += __shfl_xor(csm, 32, 64);
            if (quad == 0) {
                int i = nt * 16 + ln;
                pmaxL[i] = fmaxf(pmaxL[i], cmx);
                psumL[i] += csm;
            }
        }
    }
    __syncthreads();
    float* om = ppmax + (size_t)(g * NS + s) * FO;
    float* os = ppsum + (size_t)(g * NS + s) * FO;
    for (int col = tid; col < FO; col += 256) { om[col] = pmaxL[col]; os[col] = psumL[col]; }
}

__global__ __launch_bounds__(256) void gin_pool_both_kernel(
        const unsigned short* h1b1, const float* agg1, const short* Wbg1, const float* b21,
        const int* offs1, float* pm1, float* ps1, int nblk1,
        const unsigned short* h1b2, const float* agg2, const short* Wbg2, const float* b22,
        const int* offs2, float* pm2, float* ps2) {
    __shared__ __align__(16) short Vb[64 * 96];
    __shared__ float pmaxL[944];
    __shared__ float psumL[944];
    int bid = blockIdx.x;
    if (bid < nblk1)
        gin_pool_dev<93, 96, 930, 59, 4, 96, 94>(h1b1, agg1, Wbg1, b21, offs1,
                                                 pm1, ps1, bid, Vb, pmaxL, psumL);
    else
        gin_pool_dev<43, 64, 430, 27, 4, 48, 44>(h1b2, agg2, Wbg2, b22, offs2,
                                                 pm2, ps2, bid - nblk1, Vb, pmaxL, psumL);
}

// ---- combine partial pools -> pb bf16 [NG][KPAD] --------------------------
template<int FO, int NS, int KPAD>
__device__ __forceinline__ void pool_reduce_dev(
        const float* __restrict__ ppmax, const float* __restrict__ ppsum,
        const int* __restrict__ offs, short* __restrict__ pb, int g) {
    int cntg = offs[g + 1] - offs[g];
    float den = (float)(cntg > 0 ? cntg : 1);
    for (int col = threadIdx.x; col < KPAD; col += 256) {
        float v = 0.f;
        if (col < FO) {
            float m = 0.f;
            #pragma unroll
            for (int ss = 0; ss < NS; ++ss)
                m = fmaxf(m, ppmax[(size_t)(g * NS + ss) * FO + col]);
            v = m;
        } else if (col < 2 * FO) {
            float sm = 0.f;
            #pragma unroll
            for (int ss = 0; ss < NS; ++ss)
                sm += ppsum[(size_t)(g * NS + ss) * FO + (col - FO)];
            v = sm / den;
        }
        pb[(size_t)g * KPAD + col] = f2bf(v);
    }
}

__global__ __launch_bounds__(256) void pool_reduce_both_kernel(
        const float* pm1, const float* ps1, const int* offs1, short* pb1,
        const float* pm2, const float* ps2, const int* offs2, short* pb2) {
    int bid = blockIdx.x;
    if (bid < NG) pool_reduce_dev<930, 4, 2048>(pm1, ps1, offs1, pb1, bid);
    else          pool_reduce_dev<430, 4, 1024>(pm2, ps2, offs2, pb2, bid - NG);
}

// ---- bf16 MFMA GEMM device body, split-K ----------------------------------
template<int KPC>
__device__ __forceinline__ void fc_mfma_dev(
        const short* __restrict__ Ab, const short* __restrict__ Wb,
        float* __restrict__ partial, int KP, int NB, int bid) {
    int mb = bid & 3;
    int nb = (bid >> 2) % NB;
    int ks = (bid >> 2) / NB;
    int tid = threadIdx.x;
    int w = tid >> 6;
    int lane = tid & 63;
    int ln = lane & 15, quad = lane >> 4;
    int row = mb * 64 + w * 16 + ln;
    const short* ap = Ab + (size_t)row * KP + ks * KPC + quad * 8;
    const short* wp = Wb + (size_t)(nb * 64 + ln) * KP + ks * KPC + quad * 8;
    floatx4 acc[4];
    #pragma unroll
    for (int ns = 0; ns < 4; ++ns) acc[ns] = {0.f, 0.f, 0.f, 0.f};
    #pragma unroll
    for (int kk = 0; kk < KPC / 32; ++kk) {
        short8 a = *(const short8*)(ap + kk * 32);
        #pragma unroll
        for (int ns = 0; ns < 4; ++ns) {
            short8 b = *(const short8*)(wp + (size_t)ns * 16 * KP + kk * 32);
            acc[ns] = __builtin_amdgcn_mfma_f32_16x16x32_bf16(a, b, acc[ns], 0, 0, 0);
        }
    }
    int N = NB * 64;
    float* pp = partial + ((size_t)ks * 256 + mb * 64 + w * 16) * N + nb * 64;
    #pragma unroll
    for (int ns = 0; ns < 4; ++ns)
        #pragma unroll
        for (int r = 0; r < 4; ++r)
            pp[(quad * 4 + r) * N + ns * 16 + ln] = acc[ns][r];
}

template<int KPC1, int KPC2>
__global__ __launch_bounds__(256) void fc_mfma_both_kernel(
        const short* A1, const short* B1, float* P1, int KPa, int NBa, int nblk1,
        const short* A2, const short* B2, float* P2, int KPb, int NBb) {
    int bid = blockIdx.x;
    if (bid < nblk1) fc_mfma_dev<KPC1>(A1, B1, P1, KPa, NBa, bid);
    else             fc_mfma_dev<KPC2>(A2, B2, P2, KPb, NBb, bid - nblk1);
}

// ---- split-K reduce (both branches) ---------------------------------------
template<int KS, bool RELU, bool WBF16, bool WF32>
__global__ __launch_bounds__(256) void fc_reduce_both_kernel(
        const float* __restrict__ P1, const float* __restrict__ b1v,
        short* __restrict__ ob1, float* __restrict__ of1, int MN1, int Nn1,
        const float* __restrict__ P2, const float* __restrict__ b2v,
        short* __restrict__ ob2, float* __restrict__ of2, int MN2, int Nn2) {
    int idx = blockIdx.x * 256 + threadIdx.x;
    const float* P; const float* bias; short* ob; float* of; int MN, Nn;
    if (idx < MN1) { P = P1; bias = b1v; ob = ob1; of = of1; MN = MN1; Nn = Nn1; }
    else {
        idx -= MN1;
        if (idx >= MN2) return;
        P = P2; bias = b2v; ob = ob2; of = of2; MN = MN2; Nn = Nn2;
    }
    float v = bias[idx % Nn];
    #pragma unroll
    for (int s = 0; s < KS; ++s) v += P[(size_t)s * MN + idx];
    if (RELU) v = fmaxf(v, 0.f);
    if (WBF16) ob[idx] = f2bf(v);
    if (WF32)  of[idx] = v;
}

// ---- fused head tail (both) -----------------------------------------------
template<int KS>
__global__ __launch_bounds__(256) void head_final_both_kernel(
        const float* __restrict__ P1, const float* __restrict__ b11,
        const float* __restrict__ w21, const float* __restrict__ b21,
        float* __restrict__ z1o,
        const float* __restrict__ P2, const float* __restrict__ b12,
        const float* __restrict__ w22, const float* __restrict__ b22,
        float* __restrict__ z2o) {
    int br = blockIdx.x >> 8;
    int row = blockIdx.x & 255;
    const float* P  = br ? P2  : P1;
    const float* b1 = br ? b12 : b11;
    const float* w2 = br ? w22 : w21;
    const float* b2 = br ? b22 : b21;
    float* zo       = br ? z2o : z1o;
    int t = threadIdx.x;
    float v = b1[t];
    int idx = row * 256 + t;
    #pragma unroll
    for (int s = 0; s < KS; ++s) v += P[(size_t)s * 65536 + idx];
    v = fmaxf(v, 0.f) * w2[t];
    #pragma unroll
    for (int o = 32; o > 0; o >>= 1) v += __shfl_down(v, o, 64);
    __shared__ float red[4];
    if ((t & 63) == 0) red[t >> 6] = v;
    __syncthreads();
    if (t == 0) zo[row] = red[0] + red[1] + red[2] + red[3] + b2[0];
}

// ---------------------------------------------------------------------------
extern "C" void kernel_launch(void* const* d_in, const int* in_sizes, int n_in,
                              void* d_out, int out_size, void* d_ws, size_t ws_size,
                              hipStream_t stream) {
    (void)n_in; (void)out_size; (void)ws_size;
    const float* x      = (const float*)d_in[1];
    const int*   ei     = (const int*)  d_in[2];
    const int*   batch  = (const int*)  d_in[3];
    const float* a      = (const float*)d_in[4];
    const int*   ed     = (const int*)  d_in[5];
    const int*   c      = (const int*)  d_in[6];
    const float* W1  = (const float*)d_in[7],  *b1  = (const float*)d_in[8];
    const float* W2  = (const float*)d_in[9],  *b2  = (const float*)d_in[10];
    const float* W3  = (const float*)d_in[11], *b3  = (const float*)d_in[12];
    const float* W4  = (const float*)d_in[13], *b4  = (const float*)d_in[14];
    const float* fg_w1  = (const float*)d_in[15], *fg_b1  = (const float*)d_in[16];
    const float* fg_w2  = (const float*)d_in[17], *fg_b2  = (const float*)d_in[18];
    const float* fg1_w1 = (const float*)d_in[19], *fg1_b1 = (const float*)d_in[20];
    const float* fg1_w2 = (const float*)d_in[21], *fg1_b2 = (const float*)d_in[22];
    const float* ff_w1  = (const float*)d_in[23], *ff_b1  = (const float*)d_in[24];
    const float* ff_w2  = (const float*)d_in[25], *ff_b2  = (const float*)d_in[26];
    const float* ff1_w1 = (const float*)d_in[27], *ff1_b1 = (const float*)d_in[28];
    const float* ff1_w2 = (const float*)d_in[29], *ff1_b2 = (const float*)d_in[30];

    const int N1 = in_sizes[1] / 93;
    const int E1 = in_sizes[2] / 2;
    const int N2 = in_sizes[4] / 43;
    const int E2 = in_sizes[5] / 2;

    float* out = (float*)d_out;
    float* z   = out;
    float* xg  = out + 256;
    float* xg1 = out + 256 + 256 * 512;
    float* z1  = out + 256 + 2 * 256 * 512;

    char* wsb = (char*)d_ws;
    size_t off = 0;
    auto carve = [&](size_t bytes) {
        void* ptr = wsb + off;
        off = (off + bytes + 255) & ~(size_t)255;
        return ptr;
    };
    float*          agg1 = (float*)carve((size_t)N1 * 94 * sizeof(float));  // also fc partials
    float*          agg2 = (float*)carve((size_t)N2 * 44 * sizeof(float));
    unsigned short* xb1  = (unsigned short*)carve((size_t)N1 * 96 * 2);     // also ppmax/ppsum b1
    unsigned short* xb2  = (unsigned short*)carve((size_t)N2 * 48 * 2);     // also ppmax/ppsum b2
    unsigned short* h1b1 = (unsigned short*)carve((size_t)N1 * 96 * 2);
    unsigned short* h1b2 = (unsigned short*)carve((size_t)N2 * 48 * 2);
    short* pb1  = (short*)carve((size_t)NG * 2048 * 2);
    short* pb2  = (short*)carve((size_t)NG * 1024 * 2);
    short* t1b1 = (short*)carve((size_t)NG * 1024 * 2);
    short* t1b2 = (short*)carve((size_t)NG * 1024 * 2);
    short* xgb1 = (short*)carve((size_t)NG * 512 * 2);
    short* xgb2 = (short*)carve((size_t)NG * 512 * 2);
    short* Wbl1 = (short*)carve((size_t)96 * 96 * 2);
    short* Wbg1 = (short*)carve((size_t)944 * 96 * 2);
    short* Wbl2 = (short*)carve((size_t)48 * 64 * 2);
    short* Wbg2 = (short*)carve((size_t)432 * 64 * 2);
    short* Wb1a = (short*)carve((size_t)1024 * 2048 * 2);
    short* Wb2a = (short*)carve((size_t)512 * 1024 * 2);
    short* Wb3a = (short*)carve((size_t)256 * 512 * 2);
    short* Wb1b = (short*)carve((size_t)1024 * 1024 * 2);
    short* Wb2b = (short*)carve((size_t)512 * 1024 * 2);
    short* Wb3b = (short*)carve((size_t)256 * 512 * 2);
    int* offs1 = (int*)carve(257 * 4);
    int* offs2 = (int*)carve(257 * 4);
    int* deg   = (int*)carve((size_t)(N1 + N2) * 4);
    int* rowoff1 = (int*)carve((size_t)(N1 + 1) * 4);
    int* rowoff2 = (int*)carve((size_t)(N2 + 1) * 4);
    int* cursor1 = (int*)carve((size_t)N1 * 4);
    int* cursor2 = (int*)carve((size_t)N2 * 4);
    int* csr1  = (int*)carve((size_t)E1 * 4);
    int* csr2  = (int*)carve((size_t)E2 * 4);
    int* bsum  = (int*)carve(256 * 4);
    int* deg1 = deg, *deg2 = deg + N1;
    int* bsum1 = bsum, *bsum2 = bsum + 128;
    float* partial1 = agg1;                          // 8 MB
    float* partial2 = agg1 + (size_t)8 * 262144;     // 8 MB more (agg1 = 18.8 MB)
    float* pm1 = (float*)xb1;                        // ppmax/ppsum b1 (7.6 MB <= 9.6)
    float* ps1 = pm1 + (size_t)NG * 4 * 930;
    float* pm2 = (float*)xb2;                        // ppmax/ppsum b2 (3.5 MB <= 4.8)
    float* ps2 = pm2 + (size_t)NG * 4 * 430;

    constexpr int KS = 8;

    // ---- prologue: repacks, casts, offsets, windowed CSR build -----------
    RJobs10 jobs = {{
        { W1,     Wbl1, 93,   93,   96,   96   },
        { W2,     Wbg1, 93,   930,  944,  96   },
        { W3,     Wbl2, 43,   43,   48,   64   },
        { W4,     Wbg2, 43,   430,  432,  64   },
        { fg_w1,  Wb1a, 1860, 1024, 1024, 2048 },
        { fg_w2,  Wb2a, 1024, 512,  512,  1024 },
        { ff_w1,  Wb3a, 512,  256,  256,  512  },
        { fg1_w1, Wb1b, 860,  1024, 1024, 1024 },
        { fg1_w2, Wb2b, 1024, 512,  512,  1024 },
        { ff1_w1, Wb3b, 512,  256,  256,  512  },
    }};
    repack_all_kernel<<<dim3(512, 10), 256, 0, stream>>>(jobs);
    cast_both_kernel<<<cdiv(N1 * 96 + N2 * 48, 256), 256, 0, stream>>>(
        x, xb1, N1, a, xb2, N2);
    offs_both_kernel<<<4, 256, 0, stream>>>(batch, N1, offs1, c, N2, offs2);
    hipMemsetAsync(deg, 0, (size_t)(N1 + N2) * 4, stream);
    int nwb1 = cdiv(E1, CHK) * 8, nwb2 = cdiv(E2, CHK) * 8;
    deg_win_both_kernel<<<nwb1 + nwb2, 256, 0, stream>>>(ei, E1, N1, deg1, nwb1,
                                                         ed, E2, N2, deg2);
    int nb1 = cdiv(N1, 1024), nb2 = cdiv(N2, 1024);
    scan1_both_kernel<<<nb1 + nb2, 256, 0, stream>>>(deg1, N1, rowoff1, bsum1, nb1,
                                                     deg2, N2, rowoff2, bsum2);
    scan2_both_kernel<<<2, 64, 0, stream>>>(bsum1, nb1, bsum2, nb2);
    int nc1 = cdiv(N1, 256), nc2 = cdiv(N2, 256);
    scan3_both_kernel<<<nc1 + nc2, 256, 0, stream>>>(rowoff1, bsum1, cursor1, N1, E1,
                                                     rowoff2, bsum2, cursor2, N2, E2, nc1);
    fill_win_both_kernel<<<nwb1 + nwb2, 256, 0, stream>>>(ei, E1, N1, cursor1, csr1, nwb1,
                                                          ed, E2, N2, cursor2, csr2);

    // ---- merged GIN chains ----------------------------------------------
    int ng1 = cdiv(N1, 4), ng2 = cdiv(N2, 4);
    gather_both_kernel<<<ng1 + ng2, 256, 0, stream>>>(
        xb1, csr1, rowoff1, agg1, N1, ng1, xb2, csr2, rowoff2, agg2, N2);
    int nl1 = cdiv(N1, 64), nl2 = cdiv(N2, 64);
    gin_linear_both_kernel<<<nl1 + nl2, 256, 0, stream>>>(
        x, agg1, Wbl1, b1, h1b1, N1, nl1, a, agg2, Wbl2, b3, h1b2, N2);
    gather_both_kernel<<<ng1 + ng2, 256, 0, stream>>>(
        h1b1, csr1, rowoff1, agg1, N1, ng1, h1b2, csr2, rowoff2, agg2, N2);
    gin_pool_both_kernel<<<NG * 4 * 2, 256, 0, stream>>>(
        h1b1, agg1, Wbg1, b2, offs1, pm1, ps1, NG * 4,
        h1b2, agg2, Wbg2, b4, offs2, pm2, ps2);
    pool_reduce_both_kernel<<<2 * NG, 256, 0, stream>>>(
        pm1, ps1, offs1, pb1, pm2, ps2, offs2, pb2);

    // ---- merged FC stack -------------------------------------------------
    fc_mfma_both_kernel<256, 128><<<1024, 256, 0, stream>>>(
        pb1, Wb1a, partial1, 2048, 16, 512, pb2, Wb1b, partial2, 1024, 16);
    fc_reduce_both_kernel<KS, true, true, false><<<cdiv(2 * 256 * 1024, 256), 256, 0, stream>>>(
        partial1, fg_b1, t1b1, nullptr, 256 * 1024, 1024,
        partial2, fg1_b1, t1b2, nullptr, 256 * 1024, 1024);
    fc_mfma_both_kernel<128, 128><<<512, 256, 0, stream>>>(
        t1b1, Wb2a, partial1, 1024, 8, 256, t1b2, Wb2b, partial2, 1024, 8);
    fc_reduce_both_kernel<KS, false, true, true><<<cdiv(2 * 256 * 512, 256), 256, 0, stream>>>(
        partial1, fg_b2, xgb1, xg, 256 * 512, 512,
        partial2, fg1_b2, xgb2, xg1, 256 * 512, 512);
    fc_mfma_both_kernel<64, 64><<<256, 256, 0, stream>>>(
        xgb1, Wb3a, partial1, 512, 4, 128, xgb2, Wb3b, partial2, 512, 4);
    head_final_both_kernel<KS><<<512, 256, 0, stream>>>(
        partial1, ff_b1, ff_w2, ff_b2, z,
        partial2, ff1_b1, ff1_w2, ff1_b2, z1);
}